// Round 10
// baseline (735.673 us; speedup 1.0000x reference)
//
#include <hip/hip_runtime.h>
#include <hip/hip_bf16.h>
#include <math.h>

// Problem constants
#define CDIM 256
#define TDIM 512
#define T2   1024
#define NB   64      // N*H batches
#define MTOT 524288.0f   // T*2T elements per batch for LN

typedef __bf16 bf16x8 __attribute__((ext_vector_type(8)));
typedef float  f32x4  __attribute__((ext_vector_type(4)));
typedef ushort ushort8v __attribute__((ext_vector_type(8)));
typedef ushort ushort4v __attribute__((ext_vector_type(4)));

__device__ __forceinline__ ushort f2bf(float f) {
  union { float f; unsigned u; } v; v.f = f;
  unsigned r = v.u + 0x7fffu + ((v.u >> 16) & 1u);
  return (ushort)(r >> 16);
}
__device__ __forceinline__ float bf2f(ushort h) {
  union { unsigned u; float f; } v; v.u = ((unsigned)h) << 16;
  return v.f;
}
__device__ __forceinline__ float gelu_exact(float x) {
  return 0.5f * x * (1.0f + erff(x * 0.7071067811865475f));
}

#define TO_LDS(p)  ((__attribute__((address_space(3))) void*)(unsigned)(uintptr_t)(p))
#define TO_GLB(p)  ((const __attribute__((address_space(1))) void*)(uintptr_t)(p))
#define GLOAD_LDS16(g, l) __builtin_amdgcn_global_load_lds(TO_GLB(g), TO_LDS(l), 16, 0, 0)

#define BAR()    asm volatile("s_barrier" ::: "memory")
#define WAITL()  asm volatile("s_waitcnt lgkmcnt(0)" ::: "memory")
#define WAITV4() asm volatile("s_waitcnt vmcnt(4)" ::: "memory")
#define WAITV0() asm volatile("s_waitcnt vmcnt(0)" ::: "memory")

// ---------------------------------------------------------------- projections
// o-tiled (16 wide) + LDS-staged x chunks: x L2 traffic /16, xv reused 48x.
__global__ __launch_bounds__(256)
void proj_kernel(const float* __restrict__ x, const float* __restrict__ Wq,
                 const float* __restrict__ Wk, const float* __restrict__ Wv,
                 ushort* __restrict__ qb, ushort* __restrict__ kb,
                 float* __restrict__ vp) {
  __shared__ float xs[64 * 256];   // 64 KB: 64 c x 256 t
  int tt = threadIdx.x;
  int t0 = blockIdx.x * 256;       // 2 t-tiles
  int o0 = blockIdx.y * 16;        // 16 o-tiles
  int n  = blockIdx.z;             // 8
  const float* xn = x + (long)n * CDIM * TDIM;
  float aq[16], ak[16], av[16];
#pragma unroll
  for (int j = 0; j < 16; ++j) { aq[j] = 0.f; ak[j] = 0.f; av[j] = 0.f; }
  for (int cc = 0; cc < 256; cc += 64) {
    __syncthreads();
    for (int i = tt; i < 64 * 256; i += 256)
      xs[i] = xn[(long)(cc + (i >> 8)) * 512 + t0 + (i & 255)];
    __syncthreads();
#pragma unroll 4
    for (int c = 0; c < 64; ++c) {
      float xv = xs[c * 256 + tt];
#pragma unroll
      for (int j = 0; j < 16; ++j) {
        int wi = (o0 + j) * 256 + cc + c;
        aq[j] = fmaf(Wq[wi], xv, aq[j]);
        ak[j] = fmaf(Wk[wi], xv, ak[j]);
        av[j] = fmaf(Wv[wi], xv, av[j]);
      }
    }
  }
  int t = t0 + tt;
#pragma unroll
  for (int j = 0; j < 16; ++j) {
    int o = o0 + j, h = o >> 5, d = o & 31;
    long bidx = (((long)(n * 8 + h) * 512) + t) * 32 + d;
    qb[bidx] = f2bf(aq[j]);
    kb[bidx] = f2bf(ak[j]);
    vp[((long)n * 256 + o) * TDIM + t] = av[j];
  }
}

// ---------------------------------------- all small precompute in one kernel
__global__ __launch_bounds__(256)
void prep_kernel(const float* __restrict__ m1w0, const float* __restrict__ m2w0,
                 const float* __restrict__ m1w1, const float* __restrict__ m2w1,
                 ushort* __restrict__ cpte0, ushort* __restrict__ cpto0,
                 ushort* __restrict__ cpt1, ushort* __restrict__ cpt2,
                 ushort* __restrict__ cpt3) {
  long i = (long)blockIdx.x * 256 + threadIdx.x;
  if (i < 524288) {                 // cpte0 + cpto0
    int o = (int)(i >> 9), s = (int)(i & 511);
    int idx = (o - 2 * s) & 1023;
    cpte0[i] = f2bf(m1w0[idx]);
    cpto0[i] = f2bf(m1w0[1024 + idx]);
  } else if (i < 1572864) {         // cpt1
    long j = i - 524288;
    int o = (int)(j >> 10), kk = (int)(j & 1023);
    cpt1[j] = f2bf(m2w0[(kk & 1) * 1024 + ((o - 2 * (kk >> 1)) & 1023)]);
  } else if (i < 2621440) {         // cpt2
    long j = i - 1572864;
    int o = (int)(j >> 10), kk = (int)(j & 1023);
    cpt2[j] = f2bf(m1w1[(kk & 1) * 1024 + ((o - 2 * (kk >> 1)) & 1023)]);
  } else if (i < 3145728) {         // cpt3
    long j = i - 2621440;
    int o = (int)(j >> 10), kk = (int)(j & 1023);
    cpt3[j] = f2bf(m2w1[(kk & 1) * 512 + ((o - (kk >> 1)) & 511)]);
  }
}

// ------------------------- pdpart via prefix recurrence
__global__ __launch_bounds__(256)
void pdpart_kernel(const float* __restrict__ m1w0, float* __restrict__ pdpart) {
  __shared__ float W2[1024];
  int o = blockIdx.x * 256 + threadIdx.x;    // grid 4 x 256
  for (int i = threadIdx.x; i < 1024; i += 256) W2[i] = m1w0[1024 + i];
  __syncthreads();
  float P0 = 0.f, Tv = 0.f;
  for (int s = 0; s < 512; ++s) {
    float wv2 = W2[(o - 2 * s) & 1023];
    P0 = fmaf((float)s, wv2, P0);
    Tv += wv2;
  }
  float pd = P0 * (1.0f / 511.0f);
  pdpart[o] = pd;
  float P = 0.f;
  for (int t = 0; t < 511; ++t) {
    P += W2[(o - 2 * t) & 1023];
    pd += (2.f * P - Tv) * (1.0f / 511.0f);
    pdpart[(long)(t + 1) * 1024 + o] = pd;
  }
}

// ------------------------------------------------------------ MFMA QK^T scores
__global__ __launch_bounds__(256)
void scores_kernel(const ushort* __restrict__ qb, const ushort* __restrict__ kb,
                   ushort* __restrict__ S) {
  __shared__ ushort sm[4 * 16 * 512];   // 64 KB
  int tb = blockIdx.x;              // 8 t-blocks of 64
  int b  = blockIdx.y;              // 64
  int wv = threadIdx.x >> 6, lane = threadIdx.x & 63;
  int fr = lane & 15, fq = lane >> 4;
  int t0 = tb * 64 + wv * 16;
  bf16x8 af = *(const bf16x8*)(qb + ((long)b * 512 + t0 + fr) * 32 + fq * 8);
  const ushort* kbase = kb + (long)b * 512 * 32 + fr * 32 + fq * 8;
  char* smw = (char*)sm + wv * 16384;
  f32x4 zz = {0.f, 0.f, 0.f, 0.f};
#pragma unroll 4
  for (int st = 0; st < 32; ++st) {
    bf16x8 bfv = *(const bf16x8*)(kbase + st * 512);
    f32x4 acc = __builtin_amdgcn_mfma_f32_16x16x32_bf16(af, bfv, zz, 0, 0, 0);
#pragma unroll
    for (int r = 0; r < 4; ++r) {
      int row = fq * 4 + r;
      int byteoff = row * 1024 + (((st * 16 + fr) * 2) ^ ((row & 7) << 4));
      *(ushort*)(smw + byteoff) = f2bf(acc[r] * 0.17677669529663687f);
    }
  }
  __syncthreads();
  ushort* Sb = S + ((long)b * 512 + t0) * 512;
#pragma unroll
  for (int j = 0; j < 16; ++j) {
    int byteoff = j * 1024 + ((lane * 16) ^ ((j & 7) << 4));
    ushort8v v = *(const ushort8v*)(smw + byteoff);
    *(ushort8v*)(Sb + (long)j * 512 + lane * 8) = v;
  }
}

// =================================================================== 256² GEMM
// r7-proven structure: unswapped MFMA, scalar-store epilogue (L2 write-merge
// friendly: FETCH stays = A-read; r9's ushort4-scatter caused 64MB RMW fetch).
// Stats via wave shfl reduce + 1 atomic/wave.
#define LDS_BUF  65536
#define LDS_BOFF 32768

#define STAGE_A_(buf, h, kt) do { \
  const ushort* gA0_ = Ab + (long)((h)*128 +      sr0) * K + (kt)*64 + slog8; \
  const ushort* gA1_ = Ab + (long)((h)*128 + 64 + sr0) * K + (kt)*64 + slog8; \
  char* dA_ = ldsw + (size_t)(buf) * LDS_BUF + (h)*16384 + tid*16; \
  GLOAD_LDS16(gA0_, dA_); GLOAD_LDS16(gA1_, dA_ + 8192); } while(0)

#define STAGE_B_(buf, h, kt) do { \
  const ushort* gB0_ = Bb + (long)((h)*128 +      sr0) * K + (kt)*64 + slog8; \
  const ushort* gB1_ = Bb + (long)((h)*128 + 64 + sr0) * K + (kt)*64 + slog8; \
  char* dB_ = ldsw + (size_t)(buf) * LDS_BUF + LDS_BOFF + (h)*16384 + tid*16; \
  GLOAD_LDS16(gB0_, dB_); GLOAD_LDS16(gB1_, dB_ + 8192); } while(0)

#define LD_A_(buf, mh) do { \
  const char* aB_ = ldsc + (size_t)(buf) * LDS_BUF; \
  _Pragma("unroll") for (int mi = 0; mi < 4; ++mi) { \
    int ar_ = wm*128 + (mh)*64 + mi*16 + fr; \
    const char* rb_ = aB_ + ar_*128; int sw_ = (ar_&7)<<4; \
    af[mi][0] = *(const bf16x8*)(rb_ + ((fq*16) ^ sw_)); \
    af[mi][1] = *(const bf16x8*)(rb_ + ((64 + fq*16) ^ sw_)); \
  } } while(0)

#define LD_B_(dst, buf, nh) do { \
  const char* bB_ = ldsc + (size_t)(buf) * LDS_BUF + LDS_BOFF; \
  _Pragma("unroll") for (int ni = 0; ni < 2; ++ni) { \
    int br_ = wn*64 + (nh)*32 + ni*16 + fr; \
    const char* rb_ = bB_ + br_*128; int sw_ = (br_&7)<<4; \
    dst[ni][0] = *(const bf16x8*)(rb_ + ((fq*16) ^ sw_)); \
    dst[ni][1] = *(const bf16x8*)(rb_ + ((64 + fq*16) ^ sw_)); \
  } } while(0)

#define QUAD_(mh, nh, bfa) do { \
  __builtin_amdgcn_s_setprio(1); \
  _Pragma("unroll") for (int kk = 0; kk < 2; ++kk) \
  _Pragma("unroll") for (int mi = 0; mi < 4; ++mi) \
  _Pragma("unroll") for (int ni = 0; ni < 2; ++ni) \
    acc[(mh)*4+mi][(nh)*2+ni] = __builtin_amdgcn_mfma_f32_16x16x32_bf16( \
        af[mi][kk], bfa[ni][kk], acc[(mh)*4+mi][(nh)*2+ni], 0, 0, 0); \
  __builtin_amdgcn_s_setprio(0); } while(0)

template<int K, bool FINAL>
__global__ __launch_bounds__(512, 2)
void gemm256_kernel(const ushort* __restrict__ A, long aStride,
                    const ushort* __restrict__ BT, long bStride,
                    void* __restrict__ Out, int ncols, float* __restrict__ stats,
                    const float* __restrict__ Cadd) {
  __shared__ ushort lds[2][2][256 * 64];   // 128 KiB
  const int tid = threadIdx.x;
  const int bm = blockIdx.x, bn = blockIdx.y, b = blockIdx.z;
  constexpr int NKT2 = K >> 7;
  const ushort* Ab = A  + (long)b * aStride + (long)bm * 256 * K;
  const ushort* Bb = BT + (long)b * bStride + (long)bn * 256 * K;
  const int lane = tid & 63;
  const int fr = lane & 15, fq = lane >> 4;
  const int wid = tid >> 6, wm = wid >> 2, wn = wid & 3;
  const int sr0 = tid >> 3;
  const int slog8 = ((tid & 7) ^ (sr0 & 7)) * 8;
  const char* ldsc = (const char*)&lds[0][0][0];
  char*       ldsw = (char*)&lds[0][0][0];

  f32x4 acc[8][4] = {};
  bf16x8 af[4][2], bf0[2][2], bf1[2][2];

  STAGE_B_(0, 0, 0); STAGE_B_(0, 1, 0);
  STAGE_A_(0, 0, 0); STAGE_A_(0, 1, 0);
  STAGE_B_(1, 0, 1); STAGE_B_(1, 1, 1);
  WAITV4();
  BAR();

  for (int i = 0; i < NKT2; ++i) {
    const int t1 = 2 * i + 1, t2 = 2 * i + 2, t3 = 2 * i + 3;
    const bool st = (i < NKT2 - 1);
    LD_A_(0, 0); LD_B_(bf0, 0, 0); LD_B_(bf1, 0, 1);
    STAGE_A_(1, 0, t1); STAGE_A_(1, 1, t1);
    BAR(); WAITL();
    QUAD_(0, 0, bf0); QUAD_(0, 1, bf1);
    BAR();
    LD_A_(0, 1);
    if (st) { STAGE_B_(0, 0, t2); STAGE_B_(0, 1, t2); WAITV4(); } else { WAITV0(); }
    BAR(); WAITL();
    QUAD_(1, 1, bf1); QUAD_(1, 0, bf0);
    BAR();
    LD_A_(1, 0); LD_B_(bf0, 1, 0); LD_B_(bf1, 1, 1);
    if (st) { STAGE_A_(0, 0, t2); STAGE_A_(0, 1, t2); }
    BAR(); WAITL();
    QUAD_(0, 0, bf0); QUAD_(0, 1, bf1);
    BAR();
    LD_A_(1, 1);
    if (st) { STAGE_B_(1, 0, t3); STAGE_B_(1, 1, t3); WAITV4(); }
    BAR(); WAITL();
    QUAD_(1, 1, bf1); QUAD_(1, 0, bf0);
    BAR();
  }

  // Epilogue: thread holds C[r0+mi*16+fq*4+r][c0+ni*16+fr]  (r7 layout)
  const int r0 = bm * 256 + wm * 128;
  const int c0 = bn * 256 + wn * 64;
  if (!FINAL) {
    ushort* Yb = (ushort*)Out + (long)b * 512 * ncols;
    float s1 = 0.f, s2 = 0.f;
#pragma unroll
    for (int mi = 0; mi < 8; ++mi)
#pragma unroll
      for (int ni = 0; ni < 4; ++ni)
#pragma unroll
        for (int r = 0; r < 4; ++r) {
          float v = acc[mi][ni][r];
          int row = r0 + mi * 16 + fq * 4 + r;
          int col = c0 + ni * 16 + fr;
          if (Cadd) v += Cadd[(long)row * ncols + col];
          s1 += v; s2 += v * v;
          Yb[(long)row * ncols + col] = f2bf(v);
        }
    for (int off = 32; off > 0; off >>= 1) {
      s1 += __shfl_xor(s1, off, 64);
      s2 += __shfl_xor(s2, off, 64);
    }
    if (lane == 0) {
      atomicAdd(&stats[b * 2],     s1);
      atomicAdd(&stats[b * 2 + 1], s2);
    }
  } else {
    float* Lb = (float*)Out + (long)b * 512 * ncols;
#pragma unroll
    for (int mi = 0; mi < 8; ++mi)
#pragma unroll
      for (int ni = 0; ni < 4; ++ni)
#pragma unroll
        for (int r = 0; r < 4; ++r) {
          int row = r0 + mi * 16 + fq * 4 + r;
          int col = c0 + ni * 16 + fr;
          Lb[(long)row * ncols + col] = acc[mi][ni][r];
        }
  }
}

// --------------------------------------------- LN + gelu + pair-transpose fused
__global__ __launch_bounds__(256)
void apply_kernel(const ushort* __restrict__ Y, const float* __restrict__ stats,
                  const ushort* __restrict__ gbb, ushort* __restrict__ P) {
  __shared__ ushort2 tile[32][65];
  int ti = blockIdx.x;   // 16 t-tiles of 32
  int si = blockIdx.y;   // 8 s-tiles of 64 pairs
  int b  = blockIdx.z;   // 64
  float mu  = stats[b * 2] * (1.0f / MTOT);
  float var = stats[b * 2 + 1] * (1.0f / MTOT) - mu * mu;
  float rstd = rsqrtf(var + 1e-5f);
  const ushort* Yb = Y + (long)b * 512 * 1024;
  int tr  = threadIdx.x >> 4;
  int sp4 = (threadIdx.x & 15) * 4;
#pragma unroll
  for (int pass = 0; pass < 2; ++pass) {
    int t  = ti * 32 + pass * 16 + tr;
    int sp = si * 64 + sp4;
    ushort8v yv  = *(const ushort8v*)(Yb + (long)t * 1024 + 2 * sp);
    ushort8v gbA = *(const ushort8v*)(gbb + ((long)t * 512 + sp) * 4);
    ushort8v gbB = *(const ushort8v*)(gbb + ((long)t * 512 + sp + 2) * 4);
#pragma unroll
    for (int j = 0; j < 4; ++j) {
      int base = (j & 1) * 4;
      ushort gg0 = (j < 2) ? gbA[base + 0] : gbB[base + 0];
      ushort bb0 = (j < 2) ? gbA[base + 1] : gbB[base + 1];
      ushort gg1 = (j < 2) ? gbA[base + 2] : gbB[base + 2];
      ushort bb1 = (j < 2) ? gbA[base + 3] : gbB[base + 3];
      float y0 = (bf2f(yv[2 * j])     - mu) * rstd * bf2f(gg0) + bf2f(bb0);
      float y1 = (bf2f(yv[2 * j + 1]) - mu) * rstd * bf2f(gg1) + bf2f(bb1);
      ushort2 o; o.x = f2bf(gelu_exact(y0)); o.y = f2bf(gelu_exact(y1));
      tile[pass * 16 + tr][sp4 + j] = o;
    }
  }
  __syncthreads();
  ushort* Pb = P + (long)b * 512 * 1024;
  int srow = threadIdx.x >> 3;
  int t4   = (threadIdx.x & 7) * 4;
#pragma unroll
  for (int pass = 0; pass < 2; ++pass) {
    int scol = pass * 32 + srow;
    int s = si * 64 + scol;
    ushort2 v0 = tile[t4 + 0][scol];
    ushort2 v1 = tile[t4 + 1][scol];
    ushort2 v2 = tile[t4 + 2][scol];
    ushort2 v3 = tile[t4 + 3][scol];
    int tcol0 = ti * 32 + t4;
    ushort8v w2 = {v0.x, v0.y, v1.x, v1.y, v2.x, v2.y, v3.x, v3.y};
    *(ushort8v*)(Pb + (long)s * 1024 + 2 * tcol0) = w2;
  }
}

// -------------------- pack LN params to bf16
__global__ __launch_bounds__(256)
void prep2_kernel(const float* __restrict__ g0, const float* __restrict__ b0,
                  const float* __restrict__ g1, const float* __restrict__ b1,
                  const float* __restrict__ g2, const float* __restrict__ b2,
                  ushort* __restrict__ gbb0, ushort* __restrict__ gbb1,
                  ushort* __restrict__ gbb2) {
  long i = (long)blockIdx.x * 256 + threadIdx.x;
  int set = (int)(i >> 18);
  long j = i & 262143;
  const float* g = set == 0 ? g0 : (set == 1 ? g1 : g2);
  const float* b = set == 0 ? b0 : (set == 1 ? b1 : b2);
  ushort* gbb    = set == 0 ? gbb0 : (set == 1 ? gbb1 : gbb2);
  float2 gv = *(const float2*)(g + 2 * j);
  float2 bv = *(const float2*)(b + 2 * j);
  ushort4v o; o[0] = f2bf(gv.x); o[1] = f2bf(bv.x); o[2] = f2bf(gv.y); o[3] = f2bf(bv.y);
  *(ushort4v*)(gbb + 4 * j) = o;
}

// ----------------------------------------------------- fused softmax + attn@V
__global__ __launch_bounds__(256)
void smax_av_kernel(const float* __restrict__ L, const float* __restrict__ vp,
                    float* __restrict__ out) {
  __shared__ float Lt[32][513];
  int bh = blockIdx.x;
  int at = blockIdx.y;
  int n = bh >> 3, h = bh & 7;
  int wv = threadIdx.x >> 6, lane = threadIdx.x & 63;
  for (int rr = 0; rr < 8; ++rr) {
    int row = wv * 8 + rr;
    int a = at * 32 + row;
    const float* Lr = L + ((long)bh * 512 + a) * 512 + lane * 8;
    float4 va = *(const float4*)(Lr);
    float4 vb4 = *(const float4*)(Lr + 4);
    float e[8] = {va.x, va.y, va.z, va.w, vb4.x, vb4.y, vb4.z, vb4.w};
    float m = e[0];
#pragma unroll
    for (int j = 1; j < 8; ++j) m = fmaxf(m, e[j]);
    for (int off = 32; off > 0; off >>= 1) m = fmaxf(m, __shfl_xor(m, off, 64));
    float s = 0.f;
#pragma unroll
    for (int j = 0; j < 8; ++j) { e[j] = expf(e[j] - m); s += e[j]; }
    for (int off = 32; off > 0; off >>= 1) s += __shfl_xor(s, off, 64);
    float inv = 1.0f / s;
#pragma unroll
    for (int j = 0; j < 8; ++j) Lt[row][lane * 8 + j] = e[j] * inv;
  }
  __syncthreads();
  int r  = threadIdx.x & 31;
  int d0 = (threadIdx.x >> 5) * 4;
  const float* vb = vp + ((long)n * 256 + h * 32) * 512;
  float a0 = 0.f, a1 = 0.f, a2 = 0.f, a3 = 0.f;
  for (int bc = 0; bc < 512; bc += 4) {
    float4 v0 = *(const float4*)(vb + (d0 + 0) * 512 + bc);
    float4 v1 = *(const float4*)(vb + (d0 + 1) * 512 + bc);
    float4 v2 = *(const float4*)(vb + (d0 + 2) * 512 + bc);
    float4 v3 = *(const float4*)(vb + (d0 + 3) * 512 + bc);
    float p0 = Lt[r][bc], p1 = Lt[r][bc + 1], p2 = Lt[r][bc + 2], p3 = Lt[r][bc + 3];
    a0 = fmaf(p0, v0.x, fmaf(p1, v0.y, fmaf(p2, v0.z, fmaf(p3, v0.w, a0))));
    a1 = fmaf(p0, v1.x, fmaf(p1, v1.y, fmaf(p2, v1.z, fmaf(p3, v1.w, a1))));
    a2 = fmaf(p0, v2.x, fmaf(p1, v2.y, fmaf(p2, v2.z, fmaf(p3, v2.w, a2))));
    a3 = fmaf(p0, v3.x, fmaf(p1, v3.y, fmaf(p2, v3.z, fmaf(p3, v3.w, a3))));
  }
  int a = at * 32 + r;
  float* ob = out + ((long)n * 256 + h * 32) * 512;
  ob[(d0 + 0) * 512 + a] = a0;
  ob[(d0 + 1) * 512 + a] = a1;
  ob[(d0 + 2) * 512 + a] = a2;
  ob[(d0 + 3) * 512 + a] = a3;
}

// -------------------------------------------------------------------- launch
extern "C" void kernel_launch(void* const* d_in, const int* in_sizes, int n_in,
                              void* d_out, int out_size, void* d_ws, size_t ws_size,
                              hipStream_t stream) {
  const float* x     = (const float*)d_in[0];
  const float* Wq    = (const float*)d_in[1];
  const float* Wk    = (const float*)d_in[2];
  const float* Wv    = (const float*)d_in[3];
  const float* m1w0  = (const float*)d_in[4];
  const float* m2w0  = (const float*)d_in[5];
  const float* m1w1  = (const float*)d_in[6];
  const float* m2w1  = (const float*)d_in[7];
  const float* ln1g0 = (const float*)d_in[8];
  const float* ln1b0 = (const float*)d_in[9];
  const float* ln2g0 = (const float*)d_in[10];
  const float* ln2b0 = (const float*)d_in[11];
  const float* ln1g1 = (const float*)d_in[12];
  const float* ln1b1 = (const float*)d_in[13];

  char* w = (char*)d_ws;
  float*  vp     = (float*) (w + 0);
  ushort* qb     = (ushort*)(w + (4ull  << 20));
  ushort* kb     = (ushort*)(w + (6ull  << 20));
  float*  stats  = (float*) (w + (8ull  << 20));
  ushort* cpte0  = (ushort*)(w + (9ull  << 20));
  ushort* cpto0  = (ushort*)(w + (10ull << 20));
  ushort* cpt1   = (ushort*)(w + (11ull << 20));
  ushort* cpt2   = (ushort*)(w + (13ull << 20));
  ushort* cpt3   = (ushort*)(w + (15ull << 20));
  float*  pdpart = (float*) (w + (17ull << 20));
  ushort* bufA   = (ushort*)(w + (20ull << 20));
  ushort* bufB   = (ushort*)(w + (84ull << 20));
  ushort* gbb0   = qb;       // alias: dead after scores
  ushort* gbb1   = kb;       // alias: dead after scores
  ushort* gbb2   = cpte0;    // alias: dead after gemm1
  ushort* S      = bufA;
  float*  L      = (float*)bufB;
  float*  outp   = (float*)d_out;

  hipMemsetAsync(stats, 0, 3 * NB * 2 * sizeof(float), stream);

  proj_kernel<<<dim3(2, 16, 8), 256, 0, stream>>>(x, Wq, Wk, Wv, qb, kb, vp);
  prep_kernel<<<12288, 256, 0, stream>>>(m1w0, m2w0, m1w1, m2w1,
                                         cpte0, cpto0, cpt1, cpt2, cpt3);
  pdpart_kernel<<<4, 256, 0, stream>>>(m1w0, pdpart);
  scores_kernel<<<dim3(8, 64), 256, 0, stream>>>(qb, kb, S);
  // Y1 = S @ cpte0^T + pd_part
  gemm256_kernel<512, false><<<dim3(2, 4, 64), 512, 0, stream>>>(
      S, 512L * 512, cpte0, 0, bufB, 1024, stats, pdpart);
  prep2_kernel<<<3072, 256, 0, stream>>>(ln1g0, ln1b0, ln2g0, ln2b0, ln1g1, ln1b1,
                                         gbb0, gbb1, gbb2);
  apply_kernel<<<dim3(16, 8, 64), 256, 0, stream>>>(bufB, stats, gbb0, bufA);
  gemm256_kernel<1024, false><<<dim3(2, 4, 64), 512, 0, stream>>>(
      bufA, 512L * 1024, cpt1, 0, bufB, 1024, stats + 128, nullptr);
  apply_kernel<<<dim3(16, 8, 64), 256, 0, stream>>>(bufB, stats + 128, gbb1, bufA);
  gemm256_kernel<1024, false><<<dim3(2, 4, 64), 512, 0, stream>>>(
      bufA, 512L * 1024, cpt2, 0, bufB, 1024, stats + 256, nullptr);
  apply_kernel<<<dim3(16, 8, 64), 256, 0, stream>>>(bufB, stats + 256, gbb2, bufA);
  // L[b, a, t] = sum_k cpt3[a,k] * P3'[t,k]   (softmax-ready layout)
  gemm256_kernel<1024, true><<<dim3(2, 2, 64), 512, 0, stream>>>(
      cpt3, 0, bufA, 512L * 1024, L, 512, nullptr, nullptr);
  smax_av_kernel<<<dim3(64, 16), 256, 0, stream>>>(L, vp, outp);
}

// Round 11
// 701.714 us; speedup vs baseline: 1.0484x; 1.0484x over previous
//
#include <hip/hip_runtime.h>
#include <hip/hip_bf16.h>
#include <math.h>

// Problem constants
#define CDIM 256
#define TDIM 512
#define T2   1024
#define NB   64      // N*H batches
#define MTOT 524288.0f   // T*2T elements per batch for LN

typedef __bf16 bf16x8 __attribute__((ext_vector_type(8)));
typedef float  f32x4  __attribute__((ext_vector_type(4)));
typedef ushort ushort8v __attribute__((ext_vector_type(8)));
typedef ushort ushort4v __attribute__((ext_vector_type(4)));

__device__ __forceinline__ ushort f2bf(float f) {
  union { float f; unsigned u; } v; v.f = f;
  unsigned r = v.u + 0x7fffu + ((v.u >> 16) & 1u);
  return (ushort)(r >> 16);
}
__device__ __forceinline__ float bf2f(ushort h) {
  union { unsigned u; float f; } v; v.u = ((unsigned)h) << 16;
  return v.f;
}
__device__ __forceinline__ float gelu_exact(float x) {
  return 0.5f * x * (1.0f + erff(x * 0.7071067811865475f));
}

#define TO_LDS(p)  ((__attribute__((address_space(3))) void*)(unsigned)(uintptr_t)(p))
#define TO_GLB(p)  ((const __attribute__((address_space(1))) void*)(uintptr_t)(p))
#define GLOAD_LDS16(g, l) __builtin_amdgcn_global_load_lds(TO_GLB(g), TO_LDS(l), 16, 0, 0)

#define BAR()    asm volatile("s_barrier" ::: "memory")
#define WAITL()  asm volatile("s_waitcnt lgkmcnt(0)" ::: "memory")
#define WAITV4() asm volatile("s_waitcnt vmcnt(4)" ::: "memory")
#define WAITV0() asm volatile("s_waitcnt vmcnt(0)" ::: "memory")

// ---------------------------------------------------------------- projections
// Register o-tile of 8 (no LDS, full occupancy): 1 coalesced x load feeds 24
// FMAs; x L2 traffic /8 vs per-o kernel. r10's LDS version collapsed to
// 1 block/CU (204 us) -- reuse tiling must not destroy occupancy.
__global__ __launch_bounds__(256)
void proj_kernel(const float* __restrict__ x, const float* __restrict__ Wq,
                 const float* __restrict__ Wk, const float* __restrict__ Wv,
                 ushort* __restrict__ qb, ushort* __restrict__ kb,
                 float* __restrict__ vp) {
  int t  = blockIdx.x * 256 + threadIdx.x;   // 2 t-tiles
  int o0 = blockIdx.y * 8;                   // 32 o-tiles
  int n  = blockIdx.z;                       // 8
  const float* xn = x + (long)n * CDIM * TDIM;
  float aq[8], ak[8], av[8];
#pragma unroll
  for (int j = 0; j < 8; ++j) { aq[j] = 0.f; ak[j] = 0.f; av[j] = 0.f; }
  for (int c = 0; c < CDIM; ++c) {
    float xv = xn[(long)c * TDIM + t];
#pragma unroll
    for (int j = 0; j < 8; ++j) {
      int wi = (o0 + j) * CDIM + c;
      aq[j] = fmaf(Wq[wi], xv, aq[j]);
      ak[j] = fmaf(Wk[wi], xv, ak[j]);
      av[j] = fmaf(Wv[wi], xv, av[j]);
    }
  }
#pragma unroll
  for (int j = 0; j < 8; ++j) {
    int o = o0 + j, h = o >> 5, d = o & 31;
    long bidx = (((long)(n * 8 + h) * 512) + t) * 32 + d;
    qb[bidx] = f2bf(aq[j]);
    kb[bidx] = f2bf(ak[j]);
    vp[((long)n * 256 + o) * TDIM + t] = av[j];
  }
}

// ---------------------------------------- all small precompute in one kernel
__global__ __launch_bounds__(256)
void prep_kernel(const float* __restrict__ m1w0, const float* __restrict__ m2w0,
                 const float* __restrict__ m1w1, const float* __restrict__ m2w1,
                 ushort* __restrict__ cpte0, ushort* __restrict__ cpto0,
                 ushort* __restrict__ cpt1, ushort* __restrict__ cpt2,
                 ushort* __restrict__ cpt3) {
  long i = (long)blockIdx.x * 256 + threadIdx.x;
  if (i < 524288) {                 // cpte0 + cpto0
    int o = (int)(i >> 9), s = (int)(i & 511);
    int idx = (o - 2 * s) & 1023;
    cpte0[i] = f2bf(m1w0[idx]);
    cpto0[i] = f2bf(m1w0[1024 + idx]);
  } else if (i < 1572864) {         // cpt1
    long j = i - 524288;
    int o = (int)(j >> 10), kk = (int)(j & 1023);
    cpt1[j] = f2bf(m2w0[(kk & 1) * 1024 + ((o - 2 * (kk >> 1)) & 1023)]);
  } else if (i < 2621440) {         // cpt2
    long j = i - 1572864;
    int o = (int)(j >> 10), kk = (int)(j & 1023);
    cpt2[j] = f2bf(m1w1[(kk & 1) * 1024 + ((o - 2 * (kk >> 1)) & 1023)]);
  } else if (i < 3145728) {         // cpt3
    long j = i - 2621440;
    int o = (int)(j >> 10), kk = (int)(j & 1023);
    cpt3[j] = f2bf(m2w1[(kk & 1) * 512 + ((o - (kk >> 1)) & 511)]);
  }
}

// ------------------------- pdpart via prefix recurrence
__global__ __launch_bounds__(256)
void pdpart_kernel(const float* __restrict__ m1w0, float* __restrict__ pdpart) {
  __shared__ float W2[1024];
  int o = blockIdx.x * 256 + threadIdx.x;    // grid 4 x 256
  for (int i = threadIdx.x; i < 1024; i += 256) W2[i] = m1w0[1024 + i];
  __syncthreads();
  float P0 = 0.f, Tv = 0.f;
  for (int s = 0; s < 512; ++s) {
    float wv2 = W2[(o - 2 * s) & 1023];
    P0 = fmaf((float)s, wv2, P0);
    Tv += wv2;
  }
  float pd = P0 * (1.0f / 511.0f);
  pdpart[o] = pd;
  float P = 0.f;
  for (int t = 0; t < 511; ++t) {
    P += W2[(o - 2 * t) & 1023];
    pd += (2.f * P - Tv) * (1.0f / 511.0f);
    pdpart[(long)(t + 1) * 1024 + o] = pd;
  }
}

// ------------------------------------------------------------ MFMA QK^T scores
__global__ __launch_bounds__(256)
void scores_kernel(const ushort* __restrict__ qb, const ushort* __restrict__ kb,
                   ushort* __restrict__ S) {
  __shared__ ushort sm[4 * 16 * 512];   // 64 KB
  int tb = blockIdx.x;              // 8 t-blocks of 64
  int b  = blockIdx.y;              // 64
  int wv = threadIdx.x >> 6, lane = threadIdx.x & 63;
  int fr = lane & 15, fq = lane >> 4;
  int t0 = tb * 64 + wv * 16;
  bf16x8 af = *(const bf16x8*)(qb + ((long)b * 512 + t0 + fr) * 32 + fq * 8);
  const ushort* kbase = kb + (long)b * 512 * 32 + fr * 32 + fq * 8;
  char* smw = (char*)sm + wv * 16384;
  f32x4 zz = {0.f, 0.f, 0.f, 0.f};
#pragma unroll 4
  for (int st = 0; st < 32; ++st) {
    bf16x8 bfv = *(const bf16x8*)(kbase + st * 512);
    f32x4 acc = __builtin_amdgcn_mfma_f32_16x16x32_bf16(af, bfv, zz, 0, 0, 0);
#pragma unroll
    for (int r = 0; r < 4; ++r) {
      int row = fq * 4 + r;
      int byteoff = row * 1024 + (((st * 16 + fr) * 2) ^ ((row & 7) << 4));
      *(ushort*)(smw + byteoff) = f2bf(acc[r] * 0.17677669529663687f);
    }
  }
  __syncthreads();
  ushort* Sb = S + ((long)b * 512 + t0) * 512;
#pragma unroll
  for (int j = 0; j < 16; ++j) {
    int byteoff = j * 1024 + ((lane * 16) ^ ((j & 7) << 4));
    ushort8v v = *(const ushort8v*)(smw + byteoff);
    *(ushort8v*)(Sb + (long)j * 512 + lane * 8) = v;
  }
}

// =================================================================== 256² GEMM
// r7-proven structure: unswapped MFMA, scalar-store epilogue (L2 write-merge
// friendly). Stats via wave shfl reduce + 1 atomic/wave.
#define LDS_BUF  65536
#define LDS_BOFF 32768

#define STAGE_A_(buf, h, kt) do { \
  const ushort* gA0_ = Ab + (long)((h)*128 +      sr0) * K + (kt)*64 + slog8; \
  const ushort* gA1_ = Ab + (long)((h)*128 + 64 + sr0) * K + (kt)*64 + slog8; \
  char* dA_ = ldsw + (size_t)(buf) * LDS_BUF + (h)*16384 + tid*16; \
  GLOAD_LDS16(gA0_, dA_); GLOAD_LDS16(gA1_, dA_ + 8192); } while(0)

#define STAGE_B_(buf, h, kt) do { \
  const ushort* gB0_ = Bb + (long)((h)*128 +      sr0) * K + (kt)*64 + slog8; \
  const ushort* gB1_ = Bb + (long)((h)*128 + 64 + sr0) * K + (kt)*64 + slog8; \
  char* dB_ = ldsw + (size_t)(buf) * LDS_BUF + LDS_BOFF + (h)*16384 + tid*16; \
  GLOAD_LDS16(gB0_, dB_); GLOAD_LDS16(gB1_, dB_ + 8192); } while(0)

#define LD_A_(buf, mh) do { \
  const char* aB_ = ldsc + (size_t)(buf) * LDS_BUF; \
  _Pragma("unroll") for (int mi = 0; mi < 4; ++mi) { \
    int ar_ = wm*128 + (mh)*64 + mi*16 + fr; \
    const char* rb_ = aB_ + ar_*128; int sw_ = (ar_&7)<<4; \
    af[mi][0] = *(const bf16x8*)(rb_ + ((fq*16) ^ sw_)); \
    af[mi][1] = *(const bf16x8*)(rb_ + ((64 + fq*16) ^ sw_)); \
  } } while(0)

#define LD_B_(dst, buf, nh) do { \
  const char* bB_ = ldsc + (size_t)(buf) * LDS_BUF + LDS_BOFF; \
  _Pragma("unroll") for (int ni = 0; ni < 2; ++ni) { \
    int br_ = wn*64 + (nh)*32 + ni*16 + fr; \
    const char* rb_ = bB_ + br_*128; int sw_ = (br_&7)<<4; \
    dst[ni][0] = *(const bf16x8*)(rb_ + ((fq*16) ^ sw_)); \
    dst[ni][1] = *(const bf16x8*)(rb_ + ((64 + fq*16) ^ sw_)); \
  } } while(0)

#define QUAD_(mh, nh, bfa) do { \
  __builtin_amdgcn_s_setprio(1); \
  _Pragma("unroll") for (int kk = 0; kk < 2; ++kk) \
  _Pragma("unroll") for (int mi = 0; mi < 4; ++mi) \
  _Pragma("unroll") for (int ni = 0; ni < 2; ++ni) \
    acc[(mh)*4+mi][(nh)*2+ni] = __builtin_amdgcn_mfma_f32_16x16x32_bf16( \
        af[mi][kk], bfa[ni][kk], acc[(mh)*4+mi][(nh)*2+ni], 0, 0, 0); \
  __builtin_amdgcn_s_setprio(0); } while(0)

template<int K, bool FINAL>
__global__ __launch_bounds__(512, 2)
void gemm256_kernel(const ushort* __restrict__ A, long aStride,
                    const ushort* __restrict__ BT, long bStride,
                    void* __restrict__ Out, int ncols, float* __restrict__ stats,
                    const float* __restrict__ Cadd) {
  __shared__ ushort lds[2][2][256 * 64];   // 128 KiB
  const int tid = threadIdx.x;
  const int bm = blockIdx.x, bn = blockIdx.y, b = blockIdx.z;
  constexpr int NKT2 = K >> 7;
  const ushort* Ab = A  + (long)b * aStride + (long)bm * 256 * K;
  const ushort* Bb = BT + (long)b * bStride + (long)bn * 256 * K;
  const int lane = tid & 63;
  const int fr = lane & 15, fq = lane >> 4;
  const int wid = tid >> 6, wm = wid >> 2, wn = wid & 3;
  const int sr0 = tid >> 3;
  const int slog8 = ((tid & 7) ^ (sr0 & 7)) * 8;
  const char* ldsc = (const char*)&lds[0][0][0];
  char*       ldsw = (char*)&lds[0][0][0];

  f32x4 acc[8][4] = {};
  bf16x8 af[4][2], bf0[2][2], bf1[2][2];

  STAGE_B_(0, 0, 0); STAGE_B_(0, 1, 0);
  STAGE_A_(0, 0, 0); STAGE_A_(0, 1, 0);
  STAGE_B_(1, 0, 1); STAGE_B_(1, 1, 1);
  WAITV4();
  BAR();

  for (int i = 0; i < NKT2; ++i) {
    const int t1 = 2 * i + 1, t2 = 2 * i + 2, t3 = 2 * i + 3;
    const bool st = (i < NKT2 - 1);
    LD_A_(0, 0); LD_B_(bf0, 0, 0); LD_B_(bf1, 0, 1);
    STAGE_A_(1, 0, t1); STAGE_A_(1, 1, t1);
    BAR(); WAITL();
    QUAD_(0, 0, bf0); QUAD_(0, 1, bf1);
    BAR();
    LD_A_(0, 1);
    if (st) { STAGE_B_(0, 0, t2); STAGE_B_(0, 1, t2); WAITV4(); } else { WAITV0(); }
    BAR(); WAITL();
    QUAD_(1, 1, bf1); QUAD_(1, 0, bf0);
    BAR();
    LD_A_(1, 0); LD_B_(bf0, 1, 0); LD_B_(bf1, 1, 1);
    if (st) { STAGE_A_(0, 0, t2); STAGE_A_(0, 1, t2); }
    BAR(); WAITL();
    QUAD_(0, 0, bf0); QUAD_(0, 1, bf1);
    BAR();
    LD_A_(1, 1);
    if (st) { STAGE_B_(1, 0, t3); STAGE_B_(1, 1, t3); WAITV4(); }
    BAR(); WAITL();
    QUAD_(1, 1, bf1); QUAD_(1, 0, bf0);
    BAR();
  }

  // Epilogue: thread holds C[r0+mi*16+fq*4+r][c0+ni*16+fr]  (r7 layout)
  const int r0 = bm * 256 + wm * 128;
  const int c0 = bn * 256 + wn * 64;
  if (!FINAL) {
    ushort* Yb = (ushort*)Out + (long)b * 512 * ncols;
    float s1 = 0.f, s2 = 0.f;
#pragma unroll
    for (int mi = 0; mi < 8; ++mi)
#pragma unroll
      for (int ni = 0; ni < 4; ++ni)
#pragma unroll
        for (int r = 0; r < 4; ++r) {
          float v = acc[mi][ni][r];
          int row = r0 + mi * 16 + fq * 4 + r;
          int col = c0 + ni * 16 + fr;
          if (Cadd) v += Cadd[(long)row * ncols + col];
          s1 += v; s2 += v * v;
          Yb[(long)row * ncols + col] = f2bf(v);
        }
    for (int off = 32; off > 0; off >>= 1) {
      s1 += __shfl_xor(s1, off, 64);
      s2 += __shfl_xor(s2, off, 64);
    }
    if (lane == 0) {
      atomicAdd(&stats[b * 2],     s1);
      atomicAdd(&stats[b * 2 + 1], s2);
    }
  } else {
    float* Lb = (float*)Out + (long)b * 512 * ncols;
#pragma unroll
    for (int mi = 0; mi < 8; ++mi)
#pragma unroll
      for (int ni = 0; ni < 4; ++ni)
#pragma unroll
        for (int r = 0; r < 4; ++r) {
          int row = r0 + mi * 16 + fq * 4 + r;
          int col = c0 + ni * 16 + fr;
          Lb[(long)row * ncols + col] = acc[mi][ni][r];
        }
  }
}

// --------------------------------------------- LN + gelu + pair-transpose fused
__global__ __launch_bounds__(256)
void apply_kernel(const ushort* __restrict__ Y, const float* __restrict__ stats,
                  const ushort* __restrict__ gbb, ushort* __restrict__ P) {
  __shared__ ushort2 tile[32][65];
  int ti = blockIdx.x;   // 16 t-tiles of 32
  int si = blockIdx.y;   // 8 s-tiles of 64 pairs
  int b  = blockIdx.z;   // 64
  float mu  = stats[b * 2] * (1.0f / MTOT);
  float var = stats[b * 2 + 1] * (1.0f / MTOT) - mu * mu;
  float rstd = rsqrtf(var + 1e-5f);
  const ushort* Yb = Y + (long)b * 512 * 1024;
  int tr  = threadIdx.x >> 4;
  int sp4 = (threadIdx.x & 15) * 4;
#pragma unroll
  for (int pass = 0; pass < 2; ++pass) {
    int t  = ti * 32 + pass * 16 + tr;
    int sp = si * 64 + sp4;
    ushort8v yv  = *(const ushort8v*)(Yb + (long)t * 1024 + 2 * sp);
    ushort8v gbA = *(const ushort8v*)(gbb + ((long)t * 512 + sp) * 4);
    ushort8v gbB = *(const ushort8v*)(gbb + ((long)t * 512 + sp + 2) * 4);
#pragma unroll
    for (int j = 0; j < 4; ++j) {
      int base = (j & 1) * 4;
      ushort gg0 = (j < 2) ? gbA[base + 0] : gbB[base + 0];
      ushort bb0 = (j < 2) ? gbA[base + 1] : gbB[base + 1];
      ushort gg1 = (j < 2) ? gbA[base + 2] : gbB[base + 2];
      ushort bb1 = (j < 2) ? gbA[base + 3] : gbB[base + 3];
      float y0 = (bf2f(yv[2 * j])     - mu) * rstd * bf2f(gg0) + bf2f(bb0);
      float y1 = (bf2f(yv[2 * j + 1]) - mu) * rstd * bf2f(gg1) + bf2f(bb1);
      ushort2 o; o.x = f2bf(gelu_exact(y0)); o.y = f2bf(gelu_exact(y1));
      tile[pass * 16 + tr][sp4 + j] = o;
    }
  }
  __syncthreads();
  ushort* Pb = P + (long)b * 512 * 1024;
  int srow = threadIdx.x >> 3;
  int t4   = (threadIdx.x & 7) * 4;
#pragma unroll
  for (int pass = 0; pass < 2; ++pass) {
    int scol = pass * 32 + srow;
    int s = si * 64 + scol;
    ushort2 v0 = tile[t4 + 0][scol];
    ushort2 v1 = tile[t4 + 1][scol];
    ushort2 v2 = tile[t4 + 2][scol];
    ushort2 v3 = tile[t4 + 3][scol];
    int tcol0 = ti * 32 + t4;
    ushort8v w2 = {v0.x, v0.y, v1.x, v1.y, v2.x, v2.y, v3.x, v3.y};
    *(ushort8v*)(Pb + (long)s * 1024 + 2 * tcol0) = w2;
  }
}

// -------------------- pack LN params to bf16
__global__ __launch_bounds__(256)
void prep2_kernel(const float* __restrict__ g0, const float* __restrict__ b0,
                  const float* __restrict__ g1, const float* __restrict__ b1,
                  const float* __restrict__ g2, const float* __restrict__ b2,
                  ushort* __restrict__ gbb0, ushort* __restrict__ gbb1,
                  ushort* __restrict__ gbb2) {
  long i = (long)blockIdx.x * 256 + threadIdx.x;
  int set = (int)(i >> 18);
  long j = i & 262143;
  const float* g = set == 0 ? g0 : (set == 1 ? g1 : g2);
  const float* b = set == 0 ? b0 : (set == 1 ? b1 : b2);
  ushort* gbb    = set == 0 ? gbb0 : (set == 1 ? gbb1 : gbb2);
  float2 gv = *(const float2*)(g + 2 * j);
  float2 bv = *(const float2*)(b + 2 * j);
  ushort4v o; o[0] = f2bf(gv.x); o[1] = f2bf(bv.x); o[2] = f2bf(gv.y); o[3] = f2bf(bv.y);
  *(ushort4v*)(gbb + 4 * j) = o;
}

// ----------------------------------------------------- fused softmax + attn@V
__global__ __launch_bounds__(256)
void smax_av_kernel(const float* __restrict__ L, const float* __restrict__ vp,
                    float* __restrict__ out) {
  __shared__ float Lt[32][513];
  int bh = blockIdx.x;
  int at = blockIdx.y;
  int n = bh >> 3, h = bh & 7;
  int wv = threadIdx.x >> 6, lane = threadIdx.x & 63;
  for (int rr = 0; rr < 8; ++rr) {
    int row = wv * 8 + rr;
    int a = at * 32 + row;
    const float* Lr = L + ((long)bh * 512 + a) * 512 + lane * 8;
    float4 va = *(const float4*)(Lr);
    float4 vb4 = *(const float4*)(Lr + 4);
    float e[8] = {va.x, va.y, va.z, va.w, vb4.x, vb4.y, vb4.z, vb4.w};
    float m = e[0];
#pragma unroll
    for (int j = 1; j < 8; ++j) m = fmaxf(m, e[j]);
    for (int off = 32; off > 0; off >>= 1) m = fmaxf(m, __shfl_xor(m, off, 64));
    float s = 0.f;
#pragma unroll
    for (int j = 0; j < 8; ++j) { e[j] = expf(e[j] - m); s += e[j]; }
    for (int off = 32; off > 0; off >>= 1) s += __shfl_xor(s, off, 64);
    float inv = 1.0f / s;
#pragma unroll
    for (int j = 0; j < 8; ++j) Lt[row][lane * 8 + j] = e[j] * inv;
  }
  __syncthreads();
  int r  = threadIdx.x & 31;
  int d0 = (threadIdx.x >> 5) * 4;
  const float* vb = vp + ((long)n * 256 + h * 32) * 512;
  float a0 = 0.f, a1 = 0.f, a2 = 0.f, a3 = 0.f;
  for (int bc = 0; bc < 512; bc += 4) {
    float4 v0 = *(const float4*)(vb + (d0 + 0) * 512 + bc);
    float4 v1 = *(const float4*)(vb + (d0 + 1) * 512 + bc);
    float4 v2 = *(const float4*)(vb + (d0 + 2) * 512 + bc);
    float4 v3 = *(const float4*)(vb + (d0 + 3) * 512 + bc);
    float p0 = Lt[r][bc], p1 = Lt[r][bc + 1], p2 = Lt[r][bc + 2], p3 = Lt[r][bc + 3];
    a0 = fmaf(p0, v0.x, fmaf(p1, v0.y, fmaf(p2, v0.z, fmaf(p3, v0.w, a0))));
    a1 = fmaf(p0, v1.x, fmaf(p1, v1.y, fmaf(p2, v1.z, fmaf(p3, v1.w, a1))));
    a2 = fmaf(p0, v2.x, fmaf(p1, v2.y, fmaf(p2, v2.z, fmaf(p3, v2.w, a2))));
    a3 = fmaf(p0, v3.x, fmaf(p1, v3.y, fmaf(p2, v3.z, fmaf(p3, v3.w, a3))));
  }
  int a = at * 32 + r;
  float* ob = out + ((long)n * 256 + h * 32) * 512;
  ob[(d0 + 0) * 512 + a] = a0;
  ob[(d0 + 1) * 512 + a] = a1;
  ob[(d0 + 2) * 512 + a] = a2;
  ob[(d0 + 3) * 512 + a] = a3;
}

// -------------------------------------------------------------------- launch
extern "C" void kernel_launch(void* const* d_in, const int* in_sizes, int n_in,
                              void* d_out, int out_size, void* d_ws, size_t ws_size,
                              hipStream_t stream) {
  const float* x     = (const float*)d_in[0];
  const float* Wq    = (const float*)d_in[1];
  const float* Wk    = (const float*)d_in[2];
  const float* Wv    = (const float*)d_in[3];
  const float* m1w0  = (const float*)d_in[4];
  const float* m2w0  = (const float*)d_in[5];
  const float* m1w1  = (const float*)d_in[6];
  const float* m2w1  = (const float*)d_in[7];
  const float* ln1g0 = (const float*)d_in[8];
  const float* ln1b0 = (const float*)d_in[9];
  const float* ln2g0 = (const float*)d_in[10];
  const float* ln2b0 = (const float*)d_in[11];
  const float* ln1g1 = (const float*)d_in[12];
  const float* ln1b1 = (const float*)d_in[13];

  char* w = (char*)d_ws;
  float*  vp     = (float*) (w + 0);
  ushort* qb     = (ushort*)(w + (4ull  << 20));
  ushort* kb     = (ushort*)(w + (6ull  << 20));
  float*  stats  = (float*) (w + (8ull  << 20));
  ushort* cpte0  = (ushort*)(w + (9ull  << 20));
  ushort* cpto0  = (ushort*)(w + (10ull << 20));
  ushort* cpt1   = (ushort*)(w + (11ull << 20));
  ushort* cpt2   = (ushort*)(w + (13ull << 20));
  ushort* cpt3   = (ushort*)(w + (15ull << 20));
  float*  pdpart = (float*) (w + (17ull << 20));
  ushort* bufA   = (ushort*)(w + (20ull << 20));
  ushort* bufB   = (ushort*)(w + (84ull << 20));
  ushort* gbb0   = qb;       // alias: dead after scores
  ushort* gbb1   = kb;       // alias: dead after scores
  ushort* gbb2   = cpte0;    // alias: dead after gemm1
  ushort* S      = bufA;
  float*  L      = (float*)bufB;
  float*  outp   = (float*)d_out;

  hipMemsetAsync(stats, 0, 3 * NB * 2 * sizeof(float), stream);

  proj_kernel<<<dim3(2, 32, 8), 256, 0, stream>>>(x, Wq, Wk, Wv, qb, kb, vp);
  prep_kernel<<<12288, 256, 0, stream>>>(m1w0, m2w0, m1w1, m2w1,
                                         cpte0, cpto0, cpt1, cpt2, cpt3);
  pdpart_kernel<<<4, 256, 0, stream>>>(m1w0, pdpart);
  scores_kernel<<<dim3(8, 64), 256, 0, stream>>>(qb, kb, S);
  // Y1 = S @ cpte0^T + pd_part
  gemm256_kernel<512, false><<<dim3(2, 4, 64), 512, 0, stream>>>(
      S, 512L * 512, cpte0, 0, bufB, 1024, stats, pdpart);
  prep2_kernel<<<3072, 256, 0, stream>>>(ln1g0, ln1b0, ln2g0, ln2b0, ln1g1, ln1b1,
                                         gbb0, gbb1, gbb2);
  apply_kernel<<<dim3(16, 8, 64), 256, 0, stream>>>(bufB, stats, gbb0, bufA);
  gemm256_kernel<1024, false><<<dim3(2, 4, 64), 512, 0, stream>>>(
      bufA, 512L * 1024, cpt1, 0, bufB, 1024, stats + 128, nullptr);
  apply_kernel<<<dim3(16, 8, 64), 256, 0, stream>>>(bufB, stats + 128, gbb1, bufA);
  gemm256_kernel<1024, false><<<dim3(2, 4, 64), 512, 0, stream>>>(
      bufA, 512L * 1024, cpt2, 0, bufB, 1024, stats + 256, nullptr);
  apply_kernel<<<dim3(16, 8, 64), 256, 0, stream>>>(bufB, stats + 256, gbb2, bufA);
  // L[b, a, t] = sum_k cpt3[a,k] * P3'[t,k]   (softmax-ready layout)
  gemm256_kernel<1024, true><<<dim3(2, 2, 64), 512, 0, stream>>>(
      cpt3, 0, bufA, 512L * 1024, L, 512, nullptr, nullptr);
  smax_av_kernel<<<dim3(64, 16), 256, 0, stream>>>(L, vp, outp);
}

// Round 12
// 521.561 us; speedup vs baseline: 1.4105x; 1.3454x over previous
//
#include <hip/hip_runtime.h>
#include <hip/hip_bf16.h>
#include <math.h>

// Problem constants
#define CDIM 256
#define TDIM 512
#define T2   1024
#define NB   64      // N*H batches
#define MTOT 524288.0f   // T*2T elements per batch for LN

typedef __bf16 bf16x8 __attribute__((ext_vector_type(8)));
typedef float  f32x4  __attribute__((ext_vector_type(4)));
typedef ushort ushort8v __attribute__((ext_vector_type(8)));
typedef ushort ushort4v __attribute__((ext_vector_type(4)));

__device__ __forceinline__ ushort f2bf(float f) {
  union { float f; unsigned u; } v; v.f = f;
  unsigned r = v.u + 0x7fffu + ((v.u >> 16) & 1u);
  return (ushort)(r >> 16);
}
__device__ __forceinline__ float bf2f(ushort h) {
  union { unsigned u; float f; } v; v.u = ((unsigned)h) << 16;
  return v.f;
}
__device__ __forceinline__ float gelu_exact(float x) {
  return 0.5f * x * (1.0f + erff(x * 0.7071067811865475f));
}

#define TO_LDS(p)  ((__attribute__((address_space(3))) void*)(unsigned)(uintptr_t)(p))
#define TO_GLB(p)  ((const __attribute__((address_space(1))) void*)(uintptr_t)(p))
#define GLOAD_LDS16(g, l) __builtin_amdgcn_global_load_lds(TO_GLB(g), TO_LDS(l), 16, 0, 0)

#define BAR()    asm volatile("s_barrier" ::: "memory")
#define WAITL()  asm volatile("s_waitcnt lgkmcnt(0)" ::: "memory")
#define WAITV4() asm volatile("s_waitcnt vmcnt(4)" ::: "memory")
#define WAITV0() asm volatile("s_waitcnt vmcnt(0)" ::: "memory")

// ---------------------------------------------------------------- projections
// Per-o streaming version (proven <83 us across r2-r8; r10/r11 tiled rewrites
// both regressed -- occupancy/scratch traps).
__global__ __launch_bounds__(256)
void proj_kernel(const float* __restrict__ x, const float* __restrict__ Wq,
                 const float* __restrict__ Wk, const float* __restrict__ Wv,
                 ushort* __restrict__ qb, ushort* __restrict__ kb,
                 float* __restrict__ vp) {
  int t = blockIdx.x * 256 + threadIdx.x;
  int o = blockIdx.y;
  int n = blockIdx.z;
  const float* xn = x + (long)n * CDIM * TDIM;
  float aq = 0.f, ak = 0.f, av = 0.f;
  for (int c = 0; c < CDIM; ++c) {
    float xv = xn[c * TDIM + t];
    aq = fmaf(Wq[o * CDIM + c], xv, aq);
    ak = fmaf(Wk[o * CDIM + c], xv, ak);
    av = fmaf(Wv[o * CDIM + c], xv, av);
  }
  int h = o >> 5, d = o & 31;
  long bidx = (((long)(n * 8 + h) * 512) + t) * 32 + d;
  qb[bidx] = f2bf(aq);
  kb[bidx] = f2bf(ak);
  vp[((long)n * 256 + o) * TDIM + t] = av;
}

// ---------------------------------------- all small precompute in one kernel
__global__ __launch_bounds__(256)
void prep_kernel(const float* __restrict__ m1w0, const float* __restrict__ m2w0,
                 const float* __restrict__ m1w1, const float* __restrict__ m2w1,
                 ushort* __restrict__ cpte0, ushort* __restrict__ cpto0,
                 ushort* __restrict__ cpt1, ushort* __restrict__ cpt2,
                 ushort* __restrict__ cpt3) {
  long i = (long)blockIdx.x * 256 + threadIdx.x;
  if (i < 524288) {                 // cpte0 + cpto0
    int o = (int)(i >> 9), s = (int)(i & 511);
    int idx = (o - 2 * s) & 1023;
    cpte0[i] = f2bf(m1w0[idx]);
    cpto0[i] = f2bf(m1w0[1024 + idx]);
  } else if (i < 1572864) {         // cpt1
    long j = i - 524288;
    int o = (int)(j >> 10), kk = (int)(j & 1023);
    cpt1[j] = f2bf(m2w0[(kk & 1) * 1024 + ((o - 2 * (kk >> 1)) & 1023)]);
  } else if (i < 2621440) {         // cpt2
    long j = i - 1572864;
    int o = (int)(j >> 10), kk = (int)(j & 1023);
    cpt2[j] = f2bf(m1w1[(kk & 1) * 1024 + ((o - 2 * (kk >> 1)) & 1023)]);
  } else if (i < 3145728) {         // cpt3
    long j = i - 2621440;
    int o = (int)(j >> 10), kk = (int)(j & 1023);
    cpt3[j] = f2bf(m2w1[(kk & 1) * 512 + ((o - (kk >> 1)) & 511)]);
  }
}

// ------------------------- pdpart via prefix recurrence
__global__ __launch_bounds__(256)
void pdpart_kernel(const float* __restrict__ m1w0, float* __restrict__ pdpart) {
  __shared__ float W2[1024];
  int o = blockIdx.x * 256 + threadIdx.x;    // grid 4 x 256
  for (int i = threadIdx.x; i < 1024; i += 256) W2[i] = m1w0[1024 + i];
  __syncthreads();
  float P0 = 0.f, Tv = 0.f;
  for (int s = 0; s < 512; ++s) {
    float wv2 = W2[(o - 2 * s) & 1023];
    P0 = fmaf((float)s, wv2, P0);
    Tv += wv2;
  }
  float pd = P0 * (1.0f / 511.0f);
  pdpart[o] = pd;
  float P = 0.f;
  for (int t = 0; t < 511; ++t) {
    P += W2[(o - 2 * t) & 1023];
    pd += (2.f * P - Tv) * (1.0f / 511.0f);
    pdpart[(long)(t + 1) * 1024 + o] = pd;
  }
}

// ------------------------------------------------------------ MFMA QK^T scores
__global__ __launch_bounds__(256)
void scores_kernel(const ushort* __restrict__ qb, const ushort* __restrict__ kb,
                   ushort* __restrict__ S) {
  __shared__ ushort sm[4 * 16 * 512];   // 64 KB
  int tb = blockIdx.x;              // 8 t-blocks of 64
  int b  = blockIdx.y;              // 64
  int wv = threadIdx.x >> 6, lane = threadIdx.x & 63;
  int fr = lane & 15, fq = lane >> 4;
  int t0 = tb * 64 + wv * 16;
  bf16x8 af = *(const bf16x8*)(qb + ((long)b * 512 + t0 + fr) * 32 + fq * 8);
  const ushort* kbase = kb + (long)b * 512 * 32 + fr * 32 + fq * 8;
  char* smw = (char*)sm + wv * 16384;
  f32x4 zz = {0.f, 0.f, 0.f, 0.f};
#pragma unroll 4
  for (int st = 0; st < 32; ++st) {
    bf16x8 bfv = *(const bf16x8*)(kbase + st * 512);
    f32x4 acc = __builtin_amdgcn_mfma_f32_16x16x32_bf16(af, bfv, zz, 0, 0, 0);
#pragma unroll
    for (int r = 0; r < 4; ++r) {
      int row = fq * 4 + r;
      int byteoff = row * 1024 + (((st * 16 + fr) * 2) ^ ((row & 7) << 4));
      *(ushort*)(smw + byteoff) = f2bf(acc[r] * 0.17677669529663687f);
    }
  }
  __syncthreads();
  ushort* Sb = S + ((long)b * 512 + t0) * 512;
#pragma unroll
  for (int j = 0; j < 16; ++j) {
    int byteoff = j * 1024 + ((lane * 16) ^ ((j & 7) << 4));
    ushort8v v = *(const ushort8v*)(smw + byteoff);
    *(ushort8v*)(Sb + (long)j * 512 + lane * 8) = v;
  }
}

// =================================================================== 256² GEMM
// Exact Round-6/7/8-proven version (88.5-89.4 us x3 benches): 4-compartment
// schedule, LDS-tree stats epilogue. Byte-identical revert to test whether
// r11's 127 us GEMM was epilogue-codegen or chip-state.
#define LDS_BUF  65536
#define LDS_BOFF 32768

#define STAGE_A_(buf, h, kt) do { \
  const ushort* gA0_ = Ab + (long)((h)*128 +      sr0) * K + (kt)*64 + slog8; \
  const ushort* gA1_ = Ab + (long)((h)*128 + 64 + sr0) * K + (kt)*64 + slog8; \
  char* dA_ = ldsw + (size_t)(buf) * LDS_BUF + (h)*16384 + tid*16; \
  GLOAD_LDS16(gA0_, dA_); GLOAD_LDS16(gA1_, dA_ + 8192); } while(0)

#define STAGE_B_(buf, h, kt) do { \
  const ushort* gB0_ = Bb + (long)((h)*128 +      sr0) * K + (kt)*64 + slog8; \
  const ushort* gB1_ = Bb + (long)((h)*128 + 64 + sr0) * K + (kt)*64 + slog8; \
  char* dB_ = ldsw + (size_t)(buf) * LDS_BUF + LDS_BOFF + (h)*16384 + tid*16; \
  GLOAD_LDS16(gB0_, dB_); GLOAD_LDS16(gB1_, dB_ + 8192); } while(0)

#define LD_A_(buf, mh) do { \
  const char* aB_ = ldsc + (size_t)(buf) * LDS_BUF; \
  _Pragma("unroll") for (int mi = 0; mi < 4; ++mi) { \
    int ar_ = wm*128 + (mh)*64 + mi*16 + fr; \
    const char* rb_ = aB_ + ar_*128; int sw_ = (ar_&7)<<4; \
    af[mi][0] = *(const bf16x8*)(rb_ + ((fq*16) ^ sw_)); \
    af[mi][1] = *(const bf16x8*)(rb_ + ((64 + fq*16) ^ sw_)); \
  } } while(0)

#define LD_B_(dst, buf, nh) do { \
  const char* bB_ = ldsc + (size_t)(buf) * LDS_BUF + LDS_BOFF; \
  _Pragma("unroll") for (int ni = 0; ni < 2; ++ni) { \
    int br_ = wn*64 + (nh)*32 + ni*16 + fr; \
    const char* rb_ = bB_ + br_*128; int sw_ = (br_&7)<<4; \
    dst[ni][0] = *(const bf16x8*)(rb_ + ((fq*16) ^ sw_)); \
    dst[ni][1] = *(const bf16x8*)(rb_ + ((64 + fq*16) ^ sw_)); \
  } } while(0)

#define QUAD_(mh, nh, bfa) do { \
  __builtin_amdgcn_s_setprio(1); \
  _Pragma("unroll") for (int kk = 0; kk < 2; ++kk) \
  _Pragma("unroll") for (int mi = 0; mi < 4; ++mi) \
  _Pragma("unroll") for (int ni = 0; ni < 2; ++ni) \
    acc[(mh)*4+mi][(nh)*2+ni] = __builtin_amdgcn_mfma_f32_16x16x32_bf16( \
        af[mi][kk], bfa[ni][kk], acc[(mh)*4+mi][(nh)*2+ni], 0, 0, 0); \
  __builtin_amdgcn_s_setprio(0); } while(0)

template<int K, bool FINAL>
__global__ __launch_bounds__(512, 2)
void gemm256_kernel(const ushort* __restrict__ A, long aStride,
                    const ushort* __restrict__ BT, long bStride,
                    void* __restrict__ Out, int ncols, float* __restrict__ stats,
                    const float* __restrict__ Cadd) {
  __shared__ ushort lds[2][2][256 * 64];   // 128 KiB
  const int tid = threadIdx.x;
  const int bm = blockIdx.x, bn = blockIdx.y, b = blockIdx.z;
  constexpr int NKT2 = K >> 7;
  const ushort* Ab = A  + (long)b * aStride + (long)bm * 256 * K;
  const ushort* Bb = BT + (long)b * bStride + (long)bn * 256 * K;
  const int lane = tid & 63;
  const int fr = lane & 15, fq = lane >> 4;
  const int wid = tid >> 6, wm = wid >> 2, wn = wid & 3;
  const int sr0 = tid >> 3;
  const int slog8 = ((tid & 7) ^ (sr0 & 7)) * 8;
  const char* ldsc = (const char*)&lds[0][0][0];
  char*       ldsw = (char*)&lds[0][0][0];

  f32x4 acc[8][4] = {};
  bf16x8 af[4][2], bf0[2][2], bf1[2][2];

  STAGE_B_(0, 0, 0); STAGE_B_(0, 1, 0);
  STAGE_A_(0, 0, 0); STAGE_A_(0, 1, 0);
  STAGE_B_(1, 0, 1); STAGE_B_(1, 1, 1);
  WAITV4();
  BAR();

  for (int i = 0; i < NKT2; ++i) {
    const int t1 = 2 * i + 1, t2 = 2 * i + 2, t3 = 2 * i + 3;
    const bool st = (i < NKT2 - 1);
    LD_A_(0, 0); LD_B_(bf0, 0, 0); LD_B_(bf1, 0, 1);
    STAGE_A_(1, 0, t1); STAGE_A_(1, 1, t1);
    BAR(); WAITL();
    QUAD_(0, 0, bf0); QUAD_(0, 1, bf1);
    BAR();
    LD_A_(0, 1);
    if (st) { STAGE_B_(0, 0, t2); STAGE_B_(0, 1, t2); WAITV4(); } else { WAITV0(); }
    BAR(); WAITL();
    QUAD_(1, 1, bf1); QUAD_(1, 0, bf0);
    BAR();
    LD_A_(1, 0); LD_B_(bf0, 1, 0); LD_B_(bf1, 1, 1);
    if (st) { STAGE_A_(0, 0, t2); STAGE_A_(0, 1, t2); }
    BAR(); WAITL();
    QUAD_(0, 0, bf0); QUAD_(0, 1, bf1);
    BAR();
    LD_A_(1, 1);
    if (st) { STAGE_B_(1, 0, t3); STAGE_B_(1, 1, t3); WAITV4(); }
    BAR(); WAITL();
    QUAD_(1, 1, bf1); QUAD_(1, 0, bf0);
    BAR();
  }

  const int r0 = bm * 256 + wm * 128;
  const int c0 = bn * 256 + wn * 64;
  if (!FINAL) {
    ushort* Yb = (ushort*)Out + (long)b * 512 * ncols;
    float s1 = 0.f, s2 = 0.f;
#pragma unroll
    for (int mi = 0; mi < 8; ++mi)
#pragma unroll
      for (int ni = 0; ni < 4; ++ni)
#pragma unroll
        for (int r = 0; r < 4; ++r) {
          float v = acc[mi][ni][r];
          int row = r0 + mi * 16 + fq * 4 + r;
          int col = c0 + ni * 16 + fr;
          if (Cadd) v += Cadd[(long)row * ncols + col];
          s1 += v; s2 += v * v;
          Yb[(long)row * ncols + col] = f2bf(v);
        }
    __syncthreads();
    float* red = (float*)&lds[0][0][0];
    red[tid] = s1; red[tid + 512] = s2;
    __syncthreads();
    for (int off = 256; off > 0; off >>= 1) {
      if (tid < off) { red[tid] += red[tid + off]; red[512 + tid] += red[512 + tid + off]; }
      __syncthreads();
    }
    if (tid == 0) {
      atomicAdd(&stats[b * 2],     red[0]);
      atomicAdd(&stats[b * 2 + 1], red[512]);
    }
  } else {
    float* Lb = (float*)Out + (long)b * 512 * ncols;
#pragma unroll
    for (int mi = 0; mi < 8; ++mi)
#pragma unroll
      for (int ni = 0; ni < 4; ++ni)
#pragma unroll
        for (int r = 0; r < 4; ++r) {
          int row = r0 + mi * 16 + fq * 4 + r;
          int col = c0 + ni * 16 + fr;
          Lb[(long)row * ncols + col] = acc[mi][ni][r];
        }
  }
}

// --------------------------------------------- LN + gelu + pair-transpose fused
__global__ __launch_bounds__(256)
void apply_kernel(const ushort* __restrict__ Y, const float* __restrict__ stats,
                  const ushort* __restrict__ gbb, ushort* __restrict__ P) {
  __shared__ ushort2 tile[32][65];
  int ti = blockIdx.x;   // 16 t-tiles of 32
  int si = blockIdx.y;   // 8 s-tiles of 64 pairs
  int b  = blockIdx.z;   // 64
  float mu  = stats[b * 2] * (1.0f / MTOT);
  float var = stats[b * 2 + 1] * (1.0f / MTOT) - mu * mu;
  float rstd = rsqrtf(var + 1e-5f);
  const ushort* Yb = Y + (long)b * 512 * 1024;
  int tr  = threadIdx.x >> 4;
  int sp4 = (threadIdx.x & 15) * 4;
#pragma unroll
  for (int pass = 0; pass < 2; ++pass) {
    int t  = ti * 32 + pass * 16 + tr;
    int sp = si * 64 + sp4;
    ushort8v yv  = *(const ushort8v*)(Yb + (long)t * 1024 + 2 * sp);
    ushort8v gbA = *(const ushort8v*)(gbb + ((long)t * 512 + sp) * 4);
    ushort8v gbB = *(const ushort8v*)(gbb + ((long)t * 512 + sp + 2) * 4);
#pragma unroll
    for (int j = 0; j < 4; ++j) {
      int base = (j & 1) * 4;
      ushort gg0 = (j < 2) ? gbA[base + 0] : gbB[base + 0];
      ushort bb0 = (j < 2) ? gbA[base + 1] : gbB[base + 1];
      ushort gg1 = (j < 2) ? gbA[base + 2] : gbB[base + 2];
      ushort bb1 = (j < 2) ? gbA[base + 3] : gbB[base + 3];
      float y0 = (bf2f(yv[2 * j])     - mu) * rstd * bf2f(gg0) + bf2f(bb0);
      float y1 = (bf2f(yv[2 * j + 1]) - mu) * rstd * bf2f(gg1) + bf2f(bb1);
      ushort2 o; o.x = f2bf(gelu_exact(y0)); o.y = f2bf(gelu_exact(y1));
      tile[pass * 16 + tr][sp4 + j] = o;
    }
  }
  __syncthreads();
  ushort* Pb = P + (long)b * 512 * 1024;
  int srow = threadIdx.x >> 3;
  int t4   = (threadIdx.x & 7) * 4;
#pragma unroll
  for (int pass = 0; pass < 2; ++pass) {
    int scol = pass * 32 + srow;
    int s = si * 64 + scol;
    ushort2 v0 = tile[t4 + 0][scol];
    ushort2 v1 = tile[t4 + 1][scol];
    ushort2 v2 = tile[t4 + 2][scol];
    ushort2 v3 = tile[t4 + 3][scol];
    int tcol0 = ti * 32 + t4;
    ushort8v w2 = {v0.x, v0.y, v1.x, v1.y, v2.x, v2.y, v3.x, v3.y};
    *(ushort8v*)(Pb + (long)s * 1024 + 2 * tcol0) = w2;
  }
}

// -------------------- pack LN params to bf16
__global__ __launch_bounds__(256)
void prep2_kernel(const float* __restrict__ g0, const float* __restrict__ b0,
                  const float* __restrict__ g1, const float* __restrict__ b1,
                  const float* __restrict__ g2, const float* __restrict__ b2,
                  ushort* __restrict__ gbb0, ushort* __restrict__ gbb1,
                  ushort* __restrict__ gbb2) {
  long i = (long)blockIdx.x * 256 + threadIdx.x;
  int set = (int)(i >> 18);
  long j = i & 262143;
  const float* g = set == 0 ? g0 : (set == 1 ? g1 : g2);
  const float* b = set == 0 ? b0 : (set == 1 ? b1 : b2);
  ushort* gbb    = set == 0 ? gbb0 : (set == 1 ? gbb1 : gbb2);
  float2 gv = *(const float2*)(g + 2 * j);
  float2 bv = *(const float2*)(b + 2 * j);
  ushort4v o; o[0] = f2bf(gv.x); o[1] = f2bf(bv.x); o[2] = f2bf(gv.y); o[3] = f2bf(bv.y);
  *(ushort4v*)(gbb + 4 * j) = o;
}

// ----------------------------------------------------- fused softmax + attn@V
__global__ __launch_bounds__(256)
void smax_av_kernel(const float* __restrict__ L, const float* __restrict__ vp,
                    float* __restrict__ out) {
  __shared__ float Lt[32][513];
  int bh = blockIdx.x;
  int at = blockIdx.y;
  int n = bh >> 3, h = bh & 7;
  int wv = threadIdx.x >> 6, lane = threadIdx.x & 63;
  for (int rr = 0; rr < 8; ++rr) {
    int row = wv * 8 + rr;
    int a = at * 32 + row;
    const float* Lr = L + ((long)bh * 512 + a) * 512 + lane * 8;
    float4 va = *(const float4*)(Lr);
    float4 vb4 = *(const float4*)(Lr + 4);
    float e[8] = {va.x, va.y, va.z, va.w, vb4.x, vb4.y, vb4.z, vb4.w};
    float m = e[0];
#pragma unroll
    for (int j = 1; j < 8; ++j) m = fmaxf(m, e[j]);
    for (int off = 32; off > 0; off >>= 1) m = fmaxf(m, __shfl_xor(m, off, 64));
    float s = 0.f;
#pragma unroll
    for (int j = 0; j < 8; ++j) { e[j] = expf(e[j] - m); s += e[j]; }
    for (int off = 32; off > 0; off >>= 1) s += __shfl_xor(s, off, 64);
    float inv = 1.0f / s;
#pragma unroll
    for (int j = 0; j < 8; ++j) Lt[row][lane * 8 + j] = e[j] * inv;
  }
  __syncthreads();
  int r  = threadIdx.x & 31;
  int d0 = (threadIdx.x >> 5) * 4;
  const float* vb = vp + ((long)n * 256 + h * 32) * 512;
  float a0 = 0.f, a1 = 0.f, a2 = 0.f, a3 = 0.f;
  for (int bc = 0; bc < 512; bc += 4) {
    float4 v0 = *(const float4*)(vb + (d0 + 0) * 512 + bc);
    float4 v1 = *(const float4*)(vb + (d0 + 1) * 512 + bc);
    float4 v2 = *(const float4*)(vb + (d0 + 2) * 512 + bc);
    float4 v3 = *(const float4*)(vb + (d0 + 3) * 512 + bc);
    float p0 = Lt[r][bc], p1 = Lt[r][bc + 1], p2 = Lt[r][bc + 2], p3 = Lt[r][bc + 3];
    a0 = fmaf(p0, v0.x, fmaf(p1, v0.y, fmaf(p2, v0.z, fmaf(p3, v0.w, a0))));
    a1 = fmaf(p0, v1.x, fmaf(p1, v1.y, fmaf(p2, v1.z, fmaf(p3, v1.w, a1))));
    a2 = fmaf(p0, v2.x, fmaf(p1, v2.y, fmaf(p2, v2.z, fmaf(p3, v2.w, a2))));
    a3 = fmaf(p0, v3.x, fmaf(p1, v3.y, fmaf(p2, v3.z, fmaf(p3, v3.w, a3))));
  }
  int a = at * 32 + r;
  float* ob = out + ((long)n * 256 + h * 32) * 512;
  ob[(d0 + 0) * 512 + a] = a0;
  ob[(d0 + 1) * 512 + a] = a1;
  ob[(d0 + 2) * 512 + a] = a2;
  ob[(d0 + 3) * 512 + a] = a3;
}

// -------------------------------------------------------------------- launch
extern "C" void kernel_launch(void* const* d_in, const int* in_sizes, int n_in,
                              void* d_out, int out_size, void* d_ws, size_t ws_size,
                              hipStream_t stream) {
  const float* x     = (const float*)d_in[0];
  const float* Wq    = (const float*)d_in[1];
  const float* Wk    = (const float*)d_in[2];
  const float* Wv    = (const float*)d_in[3];
  const float* m1w0  = (const float*)d_in[4];
  const float* m2w0  = (const float*)d_in[5];
  const float* m1w1  = (const float*)d_in[6];
  const float* m2w1  = (const float*)d_in[7];
  const float* ln1g0 = (const float*)d_in[8];
  const float* ln1b0 = (const float*)d_in[9];
  const float* ln2g0 = (const float*)d_in[10];
  const float* ln2b0 = (const float*)d_in[11];
  const float* ln1g1 = (const float*)d_in[12];
  const float* ln1b1 = (const float*)d_in[13];

  char* w = (char*)d_ws;
  float*  vp     = (float*) (w + 0);
  ushort* qb     = (ushort*)(w + (4ull  << 20));
  ushort* kb     = (ushort*)(w + (6ull  << 20));
  float*  stats  = (float*) (w + (8ull  << 20));
  ushort* cpte0  = (ushort*)(w + (9ull  << 20));
  ushort* cpto0  = (ushort*)(w + (10ull << 20));
  ushort* cpt1   = (ushort*)(w + (11ull << 20));
  ushort* cpt2   = (ushort*)(w + (13ull << 20));
  ushort* cpt3   = (ushort*)(w + (15ull << 20));
  float*  pdpart = (float*) (w + (17ull << 20));
  ushort* bufA   = (ushort*)(w + (20ull << 20));
  ushort* bufB   = (ushort*)(w + (84ull << 20));
  ushort* gbb0   = qb;       // alias: dead after scores
  ushort* gbb1   = kb;       // alias: dead after scores
  ushort* gbb2   = cpte0;    // alias: dead after gemm1
  ushort* S      = bufA;
  float*  L      = (float*)bufB;
  float*  outp   = (float*)d_out;

  hipMemsetAsync(stats, 0, 3 * NB * 2 * sizeof(float), stream);

  proj_kernel<<<dim3(2, 256, 8), 256, 0, stream>>>(x, Wq, Wk, Wv, qb, kb, vp);
  prep_kernel<<<12288, 256, 0, stream>>>(m1w0, m2w0, m1w1, m2w1,
                                         cpte0, cpto0, cpt1, cpt2, cpt3);
  pdpart_kernel<<<4, 256, 0, stream>>>(m1w0, pdpart);
  scores_kernel<<<dim3(8, 64), 256, 0, stream>>>(qb, kb, S);
  // Y1 = S @ cpte0^T + pd_part
  gemm256_kernel<512, false><<<dim3(2, 4, 64), 512, 0, stream>>>(
      S, 512L * 512, cpte0, 0, bufB, 1024, stats, pdpart);
  prep2_kernel<<<3072, 256, 0, stream>>>(ln1g0, ln1b0, ln2g0, ln2b0, ln1g1, ln1b1,
                                         gbb0, gbb1, gbb2);
  apply_kernel<<<dim3(16, 8, 64), 256, 0, stream>>>(bufB, stats, gbb0, bufA);
  gemm256_kernel<1024, false><<<dim3(2, 4, 64), 512, 0, stream>>>(
      bufA, 512L * 1024, cpt1, 0, bufB, 1024, stats + 128, nullptr);
  apply_kernel<<<dim3(16, 8, 64), 256, 0, stream>>>(bufB, stats + 128, gbb1, bufA);
  gemm256_kernel<1024, false><<<dim3(2, 4, 64), 512, 0, stream>>>(
      bufA, 512L * 1024, cpt2, 0, bufB, 1024, stats + 256, nullptr);
  apply_kernel<<<dim3(16, 8, 64), 256, 0, stream>>>(bufB, stats + 256, gbb2, bufA);
  // L[b, a, t] = sum_k cpt3[a,k] * P3'[t,k]   (softmax-ready layout)
  gemm256_kernel<1024, true><<<dim3(2, 2, 64), 512, 0, stream>>>(
      cpt3, 0, bufA, 512L * 1024, L, 512, nullptr, nullptr);
  smax_av_kernel<<<dim3(64, 16), 256, 0, stream>>>(L, vp, outp);
}

// Round 13
// 514.533 us; speedup vs baseline: 1.4298x; 1.0137x over previous
//
#include <hip/hip_runtime.h>
#include <hip/hip_bf16.h>
#include <math.h>

// Problem constants
#define CDIM 256
#define TDIM 512
#define T2   1024
#define NB   64      // N*H batches
#define MTOT 524288.0f   // T*2T elements per batch for LN

typedef __bf16 bf16x8 __attribute__((ext_vector_type(8)));
typedef float  f32x4  __attribute__((ext_vector_type(4)));
typedef ushort ushort8v __attribute__((ext_vector_type(8)));
typedef ushort ushort4v __attribute__((ext_vector_type(4)));

__device__ __forceinline__ ushort f2bf(float f) {
  union { float f; unsigned u; } v; v.f = f;
  unsigned r = v.u + 0x7fffu + ((v.u >> 16) & 1u);
  return (ushort)(r >> 16);
}
__device__ __forceinline__ float bf2f(ushort h) {
  union { unsigned u; float f; } v; v.u = ((unsigned)h) << 16;
  return v.f;
}
__device__ __forceinline__ float gelu_exact(float x) {
  return 0.5f * x * (1.0f + erff(x * 0.7071067811865475f));
}

#define TO_LDS(p)  ((__attribute__((address_space(3))) void*)(unsigned)(uintptr_t)(p))
#define TO_GLB(p)  ((const __attribute__((address_space(1))) void*)(uintptr_t)(p))
#define GLOAD_LDS16(g, l) __builtin_amdgcn_global_load_lds(TO_GLB(g), TO_LDS(l), 16, 0, 0)

#define BAR()    asm volatile("s_barrier" ::: "memory")
#define WAITL()  asm volatile("s_waitcnt lgkmcnt(0)" ::: "memory")
#define WAITV4() asm volatile("s_waitcnt vmcnt(4)" ::: "memory")
#define WAITV0() asm volatile("s_waitcnt vmcnt(0)" ::: "memory")

// ---------------------------------------------------------------- projections
// Per-o streaming version (proven <89 us across r2-r8 and r12).
__global__ __launch_bounds__(256)
void proj_kernel(const float* __restrict__ x, const float* __restrict__ Wq,
                 const float* __restrict__ Wk, const float* __restrict__ Wv,
                 ushort* __restrict__ qb, ushort* __restrict__ kb,
                 float* __restrict__ vp) {
  int t = blockIdx.x * 256 + threadIdx.x;
  int o = blockIdx.y;
  int n = blockIdx.z;
  const float* xn = x + (long)n * CDIM * TDIM;
  float aq = 0.f, ak = 0.f, av = 0.f;
  for (int c = 0; c < CDIM; ++c) {
    float xv = xn[c * TDIM + t];
    aq = fmaf(Wq[o * CDIM + c], xv, aq);
    ak = fmaf(Wk[o * CDIM + c], xv, ak);
    av = fmaf(Wv[o * CDIM + c], xv, av);
  }
  int h = o >> 5, d = o & 31;
  long bidx = (((long)(n * 8 + h) * 512) + t) * 32 + d;
  qb[bidx] = f2bf(aq);
  kb[bidx] = f2bf(ak);
  vp[((long)n * 256 + o) * TDIM + t] = av;
}

// ---------------------------------------- all small precompute in one kernel
__global__ __launch_bounds__(256)
void prep_kernel(const float* __restrict__ m1w0, const float* __restrict__ m2w0,
                 const float* __restrict__ m1w1, const float* __restrict__ m2w1,
                 ushort* __restrict__ cpte0, ushort* __restrict__ cpto0,
                 ushort* __restrict__ cpt1, ushort* __restrict__ cpt2,
                 ushort* __restrict__ cpt3) {
  long i = (long)blockIdx.x * 256 + threadIdx.x;
  if (i < 524288) {                 // cpte0 + cpto0
    int o = (int)(i >> 9), s = (int)(i & 511);
    int idx = (o - 2 * s) & 1023;
    cpte0[i] = f2bf(m1w0[idx]);
    cpto0[i] = f2bf(m1w0[1024 + idx]);
  } else if (i < 1572864) {         // cpt1
    long j = i - 524288;
    int o = (int)(j >> 10), kk = (int)(j & 1023);
    cpt1[j] = f2bf(m2w0[(kk & 1) * 1024 + ((o - 2 * (kk >> 1)) & 1023)]);
  } else if (i < 2621440) {         // cpt2
    long j = i - 1572864;
    int o = (int)(j >> 10), kk = (int)(j & 1023);
    cpt2[j] = f2bf(m1w1[(kk & 1) * 1024 + ((o - 2 * (kk >> 1)) & 1023)]);
  } else if (i < 3145728) {         // cpt3
    long j = i - 2621440;
    int o = (int)(j >> 10), kk = (int)(j & 1023);
    cpt3[j] = f2bf(m2w1[(kk & 1) * 512 + ((o - (kk >> 1)) & 511)]);
  }
}

// ------------------------- pdpart via prefix recurrence
__global__ __launch_bounds__(256)
void pdpart_kernel(const float* __restrict__ m1w0, float* __restrict__ pdpart) {
  __shared__ float W2[1024];
  int o = blockIdx.x * 256 + threadIdx.x;    // grid 4 x 256
  for (int i = threadIdx.x; i < 1024; i += 256) W2[i] = m1w0[1024 + i];
  __syncthreads();
  float P0 = 0.f, Tv = 0.f;
  for (int s = 0; s < 512; ++s) {
    float wv2 = W2[(o - 2 * s) & 1023];
    P0 = fmaf((float)s, wv2, P0);
    Tv += wv2;
  }
  float pd = P0 * (1.0f / 511.0f);
  pdpart[o] = pd;
  float P = 0.f;
  for (int t = 0; t < 511; ++t) {
    P += W2[(o - 2 * t) & 1023];
    pd += (2.f * P - Tv) * (1.0f / 511.0f);
    pdpart[(long)(t + 1) * 1024 + o] = pd;
  }
}

// ------------------------------------------------------------ MFMA QK^T scores
__global__ __launch_bounds__(256)
void scores_kernel(const ushort* __restrict__ qb, const ushort* __restrict__ kb,
                   ushort* __restrict__ S) {
  __shared__ ushort sm[4 * 16 * 512];   // 64 KB
  int tb = blockIdx.x;              // 8 t-blocks of 64
  int b  = blockIdx.y;              // 64
  int wv = threadIdx.x >> 6, lane = threadIdx.x & 63;
  int fr = lane & 15, fq = lane >> 4;
  int t0 = tb * 64 + wv * 16;
  bf16x8 af = *(const bf16x8*)(qb + ((long)b * 512 + t0 + fr) * 32 + fq * 8);
  const ushort* kbase = kb + (long)b * 512 * 32 + fr * 32 + fq * 8;
  char* smw = (char*)sm + wv * 16384;
  f32x4 zz = {0.f, 0.f, 0.f, 0.f};
#pragma unroll 4
  for (int st = 0; st < 32; ++st) {
    bf16x8 bfv = *(const bf16x8*)(kbase + st * 512);
    f32x4 acc = __builtin_amdgcn_mfma_f32_16x16x32_bf16(af, bfv, zz, 0, 0, 0);
#pragma unroll
    for (int r = 0; r < 4; ++r) {
      int row = fq * 4 + r;
      int byteoff = row * 1024 + (((st * 16 + fr) * 2) ^ ((row & 7) << 4));
      *(ushort*)(smw + byteoff) = f2bf(acc[r] * 0.17677669529663687f);
    }
  }
  __syncthreads();
  ushort* Sb = S + ((long)b * 512 + t0) * 512;
#pragma unroll
  for (int j = 0; j < 16; ++j) {
    int byteoff = j * 1024 + ((lane * 16) ^ ((j & 7) << 4));
    ushort8v v = *(const ushort8v*)(smw + byteoff);
    *(ushort8v*)(Sb + (long)j * 512 + lane * 8) = v;
  }
}

// =================================================================== 256² GEMM
// r12-proven structure + T1 XCD swizzle (ONLY change this round):
// blocks sharing an A-panel (same b,bm; bn=0..BN-1) sit at stride-2 in
// dispatch order -> different XCDs -> A re-pulled from L3 4x. Remap
// w=(flat&7)*PER+(flat>>3) groups all bn-variants on one XCD (A-panel
// 512KB stays L2-resident). Bijective: nwg%8==0 for all launches.
#define LDS_BUF  65536
#define LDS_BOFF 32768

#define STAGE_A_(buf, h, kt) do { \
  const ushort* gA0_ = Ab + (long)((h)*128 +      sr0) * K + (kt)*64 + slog8; \
  const ushort* gA1_ = Ab + (long)((h)*128 + 64 + sr0) * K + (kt)*64 + slog8; \
  char* dA_ = ldsw + (size_t)(buf) * LDS_BUF + (h)*16384 + tid*16; \
  GLOAD_LDS16(gA0_, dA_); GLOAD_LDS16(gA1_, dA_ + 8192); } while(0)

#define STAGE_B_(buf, h, kt) do { \
  const ushort* gB0_ = Bb + (long)((h)*128 +      sr0) * K + (kt)*64 + slog8; \
  const ushort* gB1_ = Bb + (long)((h)*128 + 64 + sr0) * K + (kt)*64 + slog8; \
  char* dB_ = ldsw + (size_t)(buf) * LDS_BUF + LDS_BOFF + (h)*16384 + tid*16; \
  GLOAD_LDS16(gB0_, dB_); GLOAD_LDS16(gB1_, dB_ + 8192); } while(0)

#define LD_A_(buf, mh) do { \
  const char* aB_ = ldsc + (size_t)(buf) * LDS_BUF; \
  _Pragma("unroll") for (int mi = 0; mi < 4; ++mi) { \
    int ar_ = wm*128 + (mh)*64 + mi*16 + fr; \
    const char* rb_ = aB_ + ar_*128; int sw_ = (ar_&7)<<4; \
    af[mi][0] = *(const bf16x8*)(rb_ + ((fq*16) ^ sw_)); \
    af[mi][1] = *(const bf16x8*)(rb_ + ((64 + fq*16) ^ sw_)); \
  } } while(0)

#define LD_B_(dst, buf, nh) do { \
  const char* bB_ = ldsc + (size_t)(buf) * LDS_BUF + LDS_BOFF; \
  _Pragma("unroll") for (int ni = 0; ni < 2; ++ni) { \
    int br_ = wn*64 + (nh)*32 + ni*16 + fr; \
    const char* rb_ = bB_ + br_*128; int sw_ = (br_&7)<<4; \
    dst[ni][0] = *(const bf16x8*)(rb_ + ((fq*16) ^ sw_)); \
    dst[ni][1] = *(const bf16x8*)(rb_ + ((64 + fq*16) ^ sw_)); \
  } } while(0)

#define QUAD_(mh, nh, bfa) do { \
  __builtin_amdgcn_s_setprio(1); \
  _Pragma("unroll") for (int kk = 0; kk < 2; ++kk) \
  _Pragma("unroll") for (int mi = 0; mi < 4; ++mi) \
  _Pragma("unroll") for (int ni = 0; ni < 2; ++ni) \
    acc[(mh)*4+mi][(nh)*2+ni] = __builtin_amdgcn_mfma_f32_16x16x32_bf16( \
        af[mi][kk], bfa[ni][kk], acc[(mh)*4+mi][(nh)*2+ni], 0, 0, 0); \
  __builtin_amdgcn_s_setprio(0); } while(0)

template<int K, int BN, bool FINAL>
__global__ __launch_bounds__(512, 2)
void gemm256_kernel(const ushort* __restrict__ A, long aStride,
                    const ushort* __restrict__ BT, long bStride,
                    void* __restrict__ Out, int ncols, float* __restrict__ stats,
                    const float* __restrict__ Cadd) {
  __shared__ ushort lds[2][2][256 * 64];   // 128 KiB
  const int tid = threadIdx.x;
  constexpr int NKT2 = K >> 7;
  constexpr int NWG = 2 * BN * 64;
  constexpr int PER = NWG / 8;
  constexpr int BNSH = (BN == 4 ? 2 : 1);
  // T1 XCD swizzle: flat dispatch id -> work id grouping A-panel sharers
  const int flat = blockIdx.x + 2 * (blockIdx.y + BN * blockIdx.z);
  const int w    = (flat & 7) * PER + (flat >> 3);
  const int bn   = w & (BN - 1);
  const int grp  = w >> BNSH;
  const int bm   = grp & 1;
  const int b    = grp >> 1;
  const ushort* Ab = A  + (long)b * aStride + (long)bm * 256 * K;
  const ushort* Bb = BT + (long)b * bStride + (long)bn * 256 * K;
  const int lane = tid & 63;
  const int fr = lane & 15, fq = lane >> 4;
  const int wid = tid >> 6, wm = wid >> 2, wn = wid & 3;
  const int sr0 = tid >> 3;
  const int slog8 = ((tid & 7) ^ (sr0 & 7)) * 8;
  const char* ldsc = (const char*)&lds[0][0][0];
  char*       ldsw = (char*)&lds[0][0][0];

  f32x4 acc[8][4] = {};
  bf16x8 af[4][2], bf0[2][2], bf1[2][2];

  STAGE_B_(0, 0, 0); STAGE_B_(0, 1, 0);
  STAGE_A_(0, 0, 0); STAGE_A_(0, 1, 0);
  STAGE_B_(1, 0, 1); STAGE_B_(1, 1, 1);
  WAITV4();
  BAR();

  for (int i = 0; i < NKT2; ++i) {
    const int t1 = 2 * i + 1, t2 = 2 * i + 2, t3 = 2 * i + 3;
    const bool st = (i < NKT2 - 1);
    LD_A_(0, 0); LD_B_(bf0, 0, 0); LD_B_(bf1, 0, 1);
    STAGE_A_(1, 0, t1); STAGE_A_(1, 1, t1);
    BAR(); WAITL();
    QUAD_(0, 0, bf0); QUAD_(0, 1, bf1);
    BAR();
    LD_A_(0, 1);
    if (st) { STAGE_B_(0, 0, t2); STAGE_B_(0, 1, t2); WAITV4(); } else { WAITV0(); }
    BAR(); WAITL();
    QUAD_(1, 1, bf1); QUAD_(1, 0, bf0);
    BAR();
    LD_A_(1, 0); LD_B_(bf0, 1, 0); LD_B_(bf1, 1, 1);
    if (st) { STAGE_A_(0, 0, t2); STAGE_A_(0, 1, t2); }
    BAR(); WAITL();
    QUAD_(0, 0, bf0); QUAD_(0, 1, bf1);
    BAR();
    LD_A_(1, 1);
    if (st) { STAGE_B_(1, 0, t3); STAGE_B_(1, 1, t3); WAITV4(); }
    BAR(); WAITL();
    QUAD_(1, 1, bf1); QUAD_(1, 0, bf0);
    BAR();
  }

  const int r0 = bm * 256 + wm * 128;
  const int c0 = bn * 256 + wn * 64;
  if (!FINAL) {
    ushort* Yb = (ushort*)Out + (long)b * 512 * ncols;
    float s1 = 0.f, s2 = 0.f;
#pragma unroll
    for (int mi = 0; mi < 8; ++mi)
#pragma unroll
      for (int ni = 0; ni < 4; ++ni)
#pragma unroll
        for (int r = 0; r < 4; ++r) {
          float v = acc[mi][ni][r];
          int row = r0 + mi * 16 + fq * 4 + r;
          int col = c0 + ni * 16 + fr;
          if (Cadd) v += Cadd[(long)row * ncols + col];
          s1 += v; s2 += v * v;
          Yb[(long)row * ncols + col] = f2bf(v);
        }
    __syncthreads();
    float* red = (float*)&lds[0][0][0];
    red[tid] = s1; red[tid + 512] = s2;
    __syncthreads();
    for (int off = 256; off > 0; off >>= 1) {
      if (tid < off) { red[tid] += red[tid + off]; red[512 + tid] += red[512 + tid + off]; }
      __syncthreads();
    }
    if (tid == 0) {
      atomicAdd(&stats[b * 2],     red[0]);
      atomicAdd(&stats[b * 2 + 1], red[512]);
    }
  } else {
    float* Lb = (float*)Out + (long)b * 512 * ncols;
#pragma unroll
    for (int mi = 0; mi < 8; ++mi)
#pragma unroll
      for (int ni = 0; ni < 4; ++ni)
#pragma unroll
        for (int r = 0; r < 4; ++r) {
          int row = r0 + mi * 16 + fq * 4 + r;
          int col = c0 + ni * 16 + fr;
          Lb[(long)row * ncols + col] = acc[mi][ni][r];
        }
  }
}

// --------------------------------------------- LN + gelu + pair-transpose fused
__global__ __launch_bounds__(256)
void apply_kernel(const ushort* __restrict__ Y, const float* __restrict__ stats,
                  const ushort* __restrict__ gbb, ushort* __restrict__ P) {
  __shared__ ushort2 tile[32][65];
  int ti = blockIdx.x;   // 16 t-tiles of 32
  int si = blockIdx.y;   // 8 s-tiles of 64 pairs
  int b  = blockIdx.z;   // 64
  float mu  = stats[b * 2] * (1.0f / MTOT);
  float var = stats[b * 2 + 1] * (1.0f / MTOT) - mu * mu;
  float rstd = rsqrtf(var + 1e-5f);
  const ushort* Yb = Y + (long)b * 512 * 1024;
  int tr  = threadIdx.x >> 4;
  int sp4 = (threadIdx.x & 15) * 4;
#pragma unroll
  for (int pass = 0; pass < 2; ++pass) {
    int t  = ti * 32 + pass * 16 + tr;
    int sp = si * 64 + sp4;
    ushort8v yv  = *(const ushort8v*)(Yb + (long)t * 1024 + 2 * sp);
    ushort8v gbA = *(const ushort8v*)(gbb + ((long)t * 512 + sp) * 4);
    ushort8v gbB = *(const ushort8v*)(gbb + ((long)t * 512 + sp + 2) * 4);
#pragma unroll
    for (int j = 0; j < 4; ++j) {
      int base = (j & 1) * 4;
      ushort gg0 = (j < 2) ? gbA[base + 0] : gbB[base + 0];
      ushort bb0 = (j < 2) ? gbA[base + 1] : gbB[base + 1];
      ushort gg1 = (j < 2) ? gbA[base + 2] : gbB[base + 2];
      ushort bb1 = (j < 2) ? gbA[base + 3] : gbB[base + 3];
      float y0 = (bf2f(yv[2 * j])     - mu) * rstd * bf2f(gg0) + bf2f(bb0);
      float y1 = (bf2f(yv[2 * j + 1]) - mu) * rstd * bf2f(gg1) + bf2f(bb1);
      ushort2 o; o.x = f2bf(gelu_exact(y0)); o.y = f2bf(gelu_exact(y1));
      tile[pass * 16 + tr][sp4 + j] = o;
    }
  }
  __syncthreads();
  ushort* Pb = P + (long)b * 512 * 1024;
  int srow = threadIdx.x >> 3;
  int t4   = (threadIdx.x & 7) * 4;
#pragma unroll
  for (int pass = 0; pass < 2; ++pass) {
    int scol = pass * 32 + srow;
    int s = si * 64 + scol;
    ushort2 v0 = tile[t4 + 0][scol];
    ushort2 v1 = tile[t4 + 1][scol];
    ushort2 v2 = tile[t4 + 2][scol];
    ushort2 v3 = tile[t4 + 3][scol];
    int tcol0 = ti * 32 + t4;
    ushort8v w2 = {v0.x, v0.y, v1.x, v1.y, v2.x, v2.y, v3.x, v3.y};
    *(ushort8v*)(Pb + (long)s * 1024 + 2 * tcol0) = w2;
  }
}

// -------------------- pack LN params to bf16
__global__ __launch_bounds__(256)
void prep2_kernel(const float* __restrict__ g0, const float* __restrict__ b0,
                  const float* __restrict__ g1, const float* __restrict__ b1,
                  const float* __restrict__ g2, const float* __restrict__ b2,
                  ushort* __restrict__ gbb0, ushort* __restrict__ gbb1,
                  ushort* __restrict__ gbb2) {
  long i = (long)blockIdx.x * 256 + threadIdx.x;
  int set = (int)(i >> 18);
  long j = i & 262143;
  const float* g = set == 0 ? g0 : (set == 1 ? g1 : g2);
  const float* b = set == 0 ? b0 : (set == 1 ? b1 : b2);
  ushort* gbb    = set == 0 ? gbb0 : (set == 1 ? gbb1 : gbb2);
  float2 gv = *(const float2*)(g + 2 * j);
  float2 bv = *(const float2*)(b + 2 * j);
  ushort4v o; o[0] = f2bf(gv.x); o[1] = f2bf(bv.x); o[2] = f2bf(gv.y); o[3] = f2bf(bv.y);
  *(ushort4v*)(gbb + 4 * j) = o;
}

// ----------------------------------------------------- fused softmax + attn@V
__global__ __launch_bounds__(256)
void smax_av_kernel(const float* __restrict__ L, const float* __restrict__ vp,
                    float* __restrict__ out) {
  __shared__ float Lt[32][513];
  int bh = blockIdx.x;
  int at = blockIdx.y;
  int n = bh >> 3, h = bh & 7;
  int wv = threadIdx.x >> 6, lane = threadIdx.x & 63;
  for (int rr = 0; rr < 8; ++rr) {
    int row = wv * 8 + rr;
    int a = at * 32 + row;
    const float* Lr = L + ((long)bh * 512 + a) * 512 + lane * 8;
    float4 va = *(const float4*)(Lr);
    float4 vb4 = *(const float4*)(Lr + 4);
    float e[8] = {va.x, va.y, va.z, va.w, vb4.x, vb4.y, vb4.z, vb4.w};
    float m = e[0];
#pragma unroll
    for (int j = 1; j < 8; ++j) m = fmaxf(m, e[j]);
    for (int off = 32; off > 0; off >>= 1) m = fmaxf(m, __shfl_xor(m, off, 64));
    float s = 0.f;
#pragma unroll
    for (int j = 0; j < 8; ++j) { e[j] = expf(e[j] - m); s += e[j]; }
    for (int off = 32; off > 0; off >>= 1) s += __shfl_xor(s, off, 64);
    float inv = 1.0f / s;
#pragma unroll
    for (int j = 0; j < 8; ++j) Lt[row][lane * 8 + j] = e[j] * inv;
  }
  __syncthreads();
  int r  = threadIdx.x & 31;
  int d0 = (threadIdx.x >> 5) * 4;
  const float* vb = vp + ((long)n * 256 + h * 32) * 512;
  float a0 = 0.f, a1 = 0.f, a2 = 0.f, a3 = 0.f;
  for (int bc = 0; bc < 512; bc += 4) {
    float4 v0 = *(const float4*)(vb + (d0 + 0) * 512 + bc);
    float4 v1 = *(const float4*)(vb + (d0 + 1) * 512 + bc);
    float4 v2 = *(const float4*)(vb + (d0 + 2) * 512 + bc);
    float4 v3 = *(const float4*)(vb + (d0 + 3) * 512 + bc);
    float p0 = Lt[r][bc], p1 = Lt[r][bc + 1], p2 = Lt[r][bc + 2], p3 = Lt[r][bc + 3];
    a0 = fmaf(p0, v0.x, fmaf(p1, v0.y, fmaf(p2, v0.z, fmaf(p3, v0.w, a0))));
    a1 = fmaf(p0, v1.x, fmaf(p1, v1.y, fmaf(p2, v1.z, fmaf(p3, v1.w, a1))));
    a2 = fmaf(p0, v2.x, fmaf(p1, v2.y, fmaf(p2, v2.z, fmaf(p3, v2.w, a2))));
    a3 = fmaf(p0, v3.x, fmaf(p1, v3.y, fmaf(p2, v3.z, fmaf(p3, v3.w, a3))));
  }
  int a = at * 32 + r;
  float* ob = out + ((long)n * 256 + h * 32) * 512;
  ob[(d0 + 0) * 512 + a] = a0;
  ob[(d0 + 1) * 512 + a] = a1;
  ob[(d0 + 2) * 512 + a] = a2;
  ob[(d0 + 3) * 512 + a] = a3;
}

// -------------------------------------------------------------------- launch
extern "C" void kernel_launch(void* const* d_in, const int* in_sizes, int n_in,
                              void* d_out, int out_size, void* d_ws, size_t ws_size,
                              hipStream_t stream) {
  const float* x     = (const float*)d_in[0];
  const float* Wq    = (const float*)d_in[1];
  const float* Wk    = (const float*)d_in[2];
  const float* Wv    = (const float*)d_in[3];
  const float* m1w0  = (const float*)d_in[4];
  const float* m2w0  = (const float*)d_in[5];
  const float* m1w1  = (const float*)d_in[6];
  const float* m2w1  = (const float*)d_in[7];
  const float* ln1g0 = (const float*)d_in[8];
  const float* ln1b0 = (const float*)d_in[9];
  const float* ln2g0 = (const float*)d_in[10];
  const float* ln2b0 = (const float*)d_in[11];
  const float* ln1g1 = (const float*)d_in[12];
  const float* ln1b1 = (const float*)d_in[13];

  char* w = (char*)d_ws;
  float*  vp     = (float*) (w + 0);
  ushort* qb     = (ushort*)(w + (4ull  << 20));
  ushort* kb     = (ushort*)(w + (6ull  << 20));
  float*  stats  = (float*) (w + (8ull  << 20));
  ushort* cpte0  = (ushort*)(w + (9ull  << 20));
  ushort* cpto0  = (ushort*)(w + (10ull << 20));
  ushort* cpt1   = (ushort*)(w + (11ull << 20));
  ushort* cpt2   = (ushort*)(w + (13ull << 20));
  ushort* cpt3   = (ushort*)(w + (15ull << 20));
  float*  pdpart = (float*) (w + (17ull << 20));
  ushort* bufA   = (ushort*)(w + (20ull << 20));
  ushort* bufB   = (ushort*)(w + (84ull << 20));
  ushort* gbb0   = qb;       // alias: dead after scores
  ushort* gbb1   = kb;       // alias: dead after scores
  ushort* gbb2   = cpte0;    // alias: dead after gemm1
  ushort* S      = bufA;
  float*  L      = (float*)bufB;
  float*  outp   = (float*)d_out;

  hipMemsetAsync(stats, 0, 3 * NB * 2 * sizeof(float), stream);

  proj_kernel<<<dim3(2, 256, 8), 256, 0, stream>>>(x, Wq, Wk, Wv, qb, kb, vp);
  prep_kernel<<<12288, 256, 0, stream>>>(m1w0, m2w0, m1w1, m2w1,
                                         cpte0, cpto0, cpt1, cpt2, cpt3);
  pdpart_kernel<<<4, 256, 0, stream>>>(m1w0, pdpart);
  scores_kernel<<<dim3(8, 64), 256, 0, stream>>>(qb, kb, S);
  // Y1 = S @ cpte0^T + pd_part
  gemm256_kernel<512, 4, false><<<dim3(2, 4, 64), 512, 0, stream>>>(
      S, 512L * 512, cpte0, 0, bufB, 1024, stats, pdpart);
  prep2_kernel<<<3072, 256, 0, stream>>>(ln1g0, ln1b0, ln2g0, ln2b0, ln1g1, ln1b1,
                                         gbb0, gbb1, gbb2);
  apply_kernel<<<dim3(16, 8, 64), 256, 0, stream>>>(bufB, stats, gbb0, bufA);
  gemm256_kernel<1024, 4, false><<<dim3(2, 4, 64), 512, 0, stream>>>(
      bufA, 512L * 1024, cpt1, 0, bufB, 1024, stats + 128, nullptr);
  apply_kernel<<<dim3(16, 8, 64), 256, 0, stream>>>(bufB, stats + 128, gbb1, bufA);
  gemm256_kernel<1024, 4, false><<<dim3(2, 4, 64), 512, 0, stream>>>(
      bufA, 512L * 1024, cpt2, 0, bufB, 1024, stats + 256, nullptr);
  apply_kernel<<<dim3(16, 8, 64), 256, 0, stream>>>(bufB, stats + 256, gbb2, bufA);
  // L[b, a, t] = sum_k cpt3[a,k] * P3'[t,k]   (softmax-ready layout)
  gemm256_kernel<1024, 2, true><<<dim3(2, 2, 64), 512, 0, stream>>>(
      cpt3, 0, bufA, 512L * 1024, L, 512, nullptr, nullptr);
  smax_av_kernel<<<dim3(64, 16), 256, 0, stream>>>(L, vp, outp);
}